// Round 2
// baseline (2168.396 us; speedup 1.0000x reference)
//
#include <hip/hip_runtime.h>
#include <hip/hip_bf16.h>
#include <math.h>

// ---------------------------------------------------------------------------
// Problem constants (reference: NC=10, H=6, C=384, HD=64, B=16, T=197, N=196)
// SCALE = HD^-0.5 = 0.125
// ---------------------------------------------------------------------------
#define SCL 0.125f

// ---------------------------------------------------------------------------
// LayerNorm over last dim (384). One wave (64 threads) per row, 6 elems/lane.
// mode 0: cls rows   (row i -> x + i*197*384)          [26 rows]
// mode 1: xs image   (row i=b*196+n -> x[(b*197+1+n)])  [3136 rows]
// mode 2: anchor img (row i=b*196+n -> x[((16+b)*197+1+n)]) [1960 rows]
// mode 3: plain contiguous rows (src = x + i*384)
// ---------------------------------------------------------------------------
__global__ void ln_kernel(const float* __restrict__ x, float* __restrict__ out,
                          const float* __restrict__ g, const float* __restrict__ bt,
                          int mode) {
    const int row = blockIdx.x;
    const int lane = threadIdx.x;           // 64 threads
    const float* src;
    if (mode == 0)      src = x + (size_t)row * (197 * 384);
    else if (mode == 1) { int b = row / 196, n = row % 196; src = x + (size_t)(b * 197 + 1 + n) * 384; }
    else if (mode == 2) { int b = row / 196, n = row % 196; src = x + (size_t)((16 + b) * 197 + 1 + n) * 384; }
    else                src = x + (size_t)row * 384;

    float v[6];
    float s = 0.f, s2 = 0.f;
#pragma unroll
    for (int j = 0; j < 6; j++) {
        v[j] = src[lane + j * 64];
        s += v[j];
        s2 += v[j] * v[j];
    }
#pragma unroll
    for (int o = 32; o; o >>= 1) {
        s  += __shfl_xor(s, o);
        s2 += __shfl_xor(s2, o);
    }
    const float mu = s * (1.f / 384.f);
    const float var = s2 * (1.f / 384.f) - mu * mu;
    const float rs = 1.f / sqrtf(var + 1e-5f);
    float* dst = out + (size_t)row * 384;
#pragma unroll
    for (int j = 0; j < 6; j++) {
        const int c = lane + j * 64;
        dst[c] = (v[j] - mu) * rs * g[c] + bt[c];
    }
}

// ---------------------------------------------------------------------------
// Tiny GEMM: one thread per output element. C[m*ldc+n] = A[m,:K]@B[:,n] (+bias)
// Used for the cls-token path (M<=16).
// ---------------------------------------------------------------------------
__global__ void gemm_small(const float* __restrict__ A, const float* __restrict__ B,
                           const float* __restrict__ bias, float* __restrict__ C,
                           int M, int N, int K, int ldc) {
    const int e = blockIdx.x * 256 + threadIdx.x;
    if (e >= M * N) return;
    const int m = e / N, n = e % N;
    float acc = bias ? bias[n] : 0.f;
    const float* a = A + (size_t)m * K;
    for (int k = 0; k < K; k++) acc += a[k] * B[(size_t)k * N + n];
    C[(size_t)m * ldc + n] = acc;
}

// ---------------------------------------------------------------------------
// cls attention: logits[n,h] = S * q[n,h,:].k[b,h,:]; softmax over n (10);
// store probs flat (reference (n,h) order) and cls_pre[b,:] = sum_n p*v.
// One block per b (16), 64 threads.
// ---------------------------------------------------------------------------
__global__ void attn_cls_kernel(const float* __restrict__ qv, const float* __restrict__ kcls,
                                float* __restrict__ aflat, float* __restrict__ cls_pre) {
    const int b = blockIdx.x;
    const int t = threadIdx.x;  // 64
    __shared__ float kb[384];
    __shared__ float pl[60];
#pragma unroll
    for (int j = 0; j < 6; j++) kb[t + j * 64] = kcls[b * 384 + t + j * 64];
    __syncthreads();
    if (t < 60) {
        const int n = t / 6, h = t % 6;
        float acc = 0.f;
        for (int d = 0; d < 64; d++) acc += qv[n * 768 + h * 64 + d] * kb[h * 64 + d];
        pl[t] = acc * SCL;
    }
    __syncthreads();
    if (t < 6) {
        float m = -1e30f;
        for (int n = 0; n < 10; n++) m = fmaxf(m, pl[n * 6 + t]);
        float p[10], sum = 0.f;
        for (int n = 0; n < 10; n++) { p[n] = expf(pl[n * 6 + t] - m); sum += p[n]; }
        const float inv = 1.f / sum;
        for (int n = 0; n < 10; n++) {
            const float pr = p[n] * inv;
            pl[n * 6 + t] = pr;
            aflat[b * 60 + n * 6 + t] = pr;   // reference flat (n,h) order
        }
    }
    __syncthreads();
#pragma unroll
    for (int j = 0; j < 6; j++) {
        const int c = t + j * 64;
        const int h = c >> 6;
        float acc = 0.f;
        for (int n = 0; n < 10; n++) acc += pl[n * 6 + h] * qv[n * 768 + 384 + c];
        cls_pre[b * 384 + c] = acc;
    }
}

// ---------------------------------------------------------------------------
// Tiled fp32 GEMM: C = act(A@B + bias) (+ residual). BM=BN=128, BK=8,
// 256 threads, 8x8 per thread. N must be /128, K /8; M bounds-checked.
// REMAP: row r -> r + r/196 + 1 for BOTH residual source and C (maps
// (b,n) image rows into the (b,197) token layout, skipping token 0).
// ACT: 0 none, 1 exact GELU.
// ---------------------------------------------------------------------------
__device__ __forceinline__ float gelu_exact(float v) {
    return 0.5f * v * (1.f + erff(v * 0.70710678118654752f));
}

template <int ACT, bool REMAP>
__launch_bounds__(256)
__global__ void gemm128(const float* __restrict__ A, const float* __restrict__ Bm,
                        const float* __restrict__ bias, const float* __restrict__ res,
                        float* __restrict__ C, int M, int N, int K) {
    __shared__ float As[8][132];
    __shared__ float Bs[8][132];
    const int n0 = blockIdx.x * 128, m0 = blockIdx.y * 128;
    const int t = threadIdx.x;
    const int tx = t & 15, ty = t >> 4;
    float acc[8][8];
#pragma unroll
    for (int i = 0; i < 8; i++)
#pragma unroll
        for (int j = 0; j < 8; j++) acc[i][j] = 0.f;

    const int am = t >> 1, akq = (t & 1) * 4;
    const int bkk = t >> 5, bnq = (t & 31) * 4;

    for (int k0 = 0; k0 < K; k0 += 8) {
        float4 f = make_float4(0.f, 0.f, 0.f, 0.f);
        const int arow = m0 + am;
        if (arow < M) f = *(const float4*)(A + (size_t)arow * K + k0 + akq);
        As[akq][am] = f.x; As[akq + 1][am] = f.y; As[akq + 2][am] = f.z; As[akq + 3][am] = f.w;
        const float4 gq = *(const float4*)(Bm + (size_t)(k0 + bkk) * N + n0 + bnq);
        *(float4*)&Bs[bkk][bnq] = gq;
        __syncthreads();
#pragma unroll
        for (int kk = 0; kk < 8; kk++) {
            float a[8], bb[8];
            *(float4*)&a[0]  = *(float4*)&As[kk][ty * 8];
            *(float4*)&a[4]  = *(float4*)&As[kk][ty * 8 + 4];
            *(float4*)&bb[0] = *(float4*)&Bs[kk][tx * 8];
            *(float4*)&bb[4] = *(float4*)&Bs[kk][tx * 8 + 4];
#pragma unroll
            for (int i = 0; i < 8; i++)
#pragma unroll
                for (int j = 0; j < 8; j++) acc[i][j] += a[i] * bb[j];
        }
        __syncthreads();
    }

#pragma unroll
    for (int i = 0; i < 8; i++) {
        const int row = m0 + ty * 8 + i;
        if (row >= M) break;
        const int crow = REMAP ? (row + row / 196 + 1) : row;
#pragma unroll
        for (int j = 0; j < 8; j += 4) {
            const int col = n0 + tx * 8 + j;
            float4 v;
            v.x = acc[i][j]; v.y = acc[i][j + 1]; v.z = acc[i][j + 2]; v.w = acc[i][j + 3];
            if (bias) {
                v.x += bias[col]; v.y += bias[col + 1]; v.z += bias[col + 2]; v.w += bias[col + 3];
            }
            if (ACT == 1) {
                v.x = gelu_exact(v.x); v.y = gelu_exact(v.y);
                v.z = gelu_exact(v.z); v.w = gelu_exact(v.w);
            }
            if (res) {
                const float4 r = *(const float4*)(res + (size_t)crow * N + col);
                v.x += r.x; v.y += r.y; v.z += r.z; v.w += r.w;
            }
            *(float4*)(C + (size_t)crow * N + col) = v;
        }
    }
}

// ---------------------------------------------------------------------------
// The rectified-attention chain.
// tmp[b,h,n,k] = sum_c w2[b,h,c] * sum_m relu(-S*qh[b,h,n,:].kh[c,h,m,:])
//                                        * relu( S*k2[c,h,m,:].q2[b,h,k,:])
// Grid: x = (n-tile in {0,1}) | (c-group<<1), y = h, z = b. 512 threads.
// Block owns 98 n-rows x all 196 k-cols, loops c over its 5-c group and
// m in 7 tiles of 28. w2 folded into L. c-group g writes tmp{g}.
// LDS: 125.8 KiB -> 1 block/CU.
// ---------------------------------------------------------------------------
__launch_bounds__(512, 1)
__global__ void chain_kernel(const float* __restrict__ QH, const float* __restrict__ KH,
                             const float* __restrict__ Q2, const float* __restrict__ K2,
                             const float* __restrict__ aflat,
                             float* __restrict__ tmp0, float* __restrict__ tmp1) {
    const int b = blockIdx.z, h = blockIdx.y;
    const int ntile = blockIdx.x & 1, cg = blockIdx.x >> 1;
    const int n0 = ntile * 98;
    const int t = threadIdx.x;

    __shared__ float qs[98][68];     // qh rows n0..n0+97           (26.6 KB)
    __shared__ float q2s[196][68];   // q2 all 196 rows             (53.3 KB)
    __shared__ float khs[28][68];    // kh m-tile                   ( 7.6 KB)
    __shared__ float k2s[28][68];    // k2 m-tile                   ( 7.6 KB)
    __shared__ float LtT[28][100];   // L tile, transposed [m][n]   (11.2 KB)
    __shared__ float Rt[28][200];    // R tile [m][k]               (22.4 KB)

    // Stage qh tile and full q2 (f4 granularity; cols 64..67 are pad).
    for (int e = t; e < 98 * 16; e += 512) {
        const int i = e >> 4, d4 = (e & 15) << 2;
        const float4 f = *(const float4*)(QH + (size_t)(b * 196 + n0 + i) * 384 + h * 64 + d4);
        qs[i][d4] = f.x; qs[i][d4 + 1] = f.y; qs[i][d4 + 2] = f.z; qs[i][d4 + 3] = f.w;
    }
    for (int e = t; e < 196 * 16; e += 512) {
        const int k = e >> 4, d4 = (e & 15) << 2;
        const float4 f = *(const float4*)(Q2 + (size_t)(b * 196 + k) * 384 + h * 64 + d4);
        q2s[k][d4] = f.x; q2s[k][d4 + 1] = f.y; q2s[k][d4 + 2] = f.z; q2s[k][d4 + 3] = f.w;
    }

    float acc[7][7];
#pragma unroll
    for (int i = 0; i < 7; i++)
#pragma unroll
        for (int j = 0; j < 7; j++) acc[i][j] = 0.f;

    const int c0 = cg * 5;
    for (int ci = 0; ci < 5; ci++) {
        const int c = c0 + ci;
        // w2[b,h,c] via the reference's reshape (NOT transpose) of attn_cls:
        const float w = aflat[b * 60 + h * 10 + c];
        for (int mt = 0; mt < 7; mt++) {
            const int m0 = mt * 28;
            __syncthreads();   // prev mm done with LtT/Rt; safe to restage
            for (int e = t; e < 28 * 16; e += 512) {
                const int j = e >> 4, d4 = (e & 15) << 2;
                const float4 f1 = *(const float4*)(KH + (size_t)(c * 196 + m0 + j) * 384 + h * 64 + d4);
                khs[j][d4] = f1.x; khs[j][d4 + 1] = f1.y; khs[j][d4 + 2] = f1.z; khs[j][d4 + 3] = f1.w;
                const float4 f2 = *(const float4*)(K2 + (size_t)(c * 196 + m0 + j) * 384 + h * 64 + d4);
                k2s[j][d4] = f2.x; k2s[j][d4 + 1] = f2.y; k2s[j][d4 + 2] = f2.z; k2s[j][d4 + 3] = f2.w;
            }
            __syncthreads();
            if (t < 196) {
                // L: 98x28, 7 rows x 2 cols per thread (14 i-groups x 14 j-pairs)
                const int ig = t / 14, jp = t % 14;
                float a0[7], a1[7];
#pragma unroll
                for (int i = 0; i < 7; i++) { a0[i] = 0.f; a1[i] = 0.f; }
                for (int d4 = 0; d4 < 64; d4 += 4) {
                    const float4 kj0 = *(const float4*)&khs[jp * 2][d4];
                    const float4 kj1 = *(const float4*)&khs[jp * 2 + 1][d4];
#pragma unroll
                    for (int i = 0; i < 7; i++) {
                        const float4 q = *(const float4*)&qs[ig * 7 + i][d4];
                        a0[i] += q.x * kj0.x + q.y * kj0.y + q.z * kj0.z + q.w * kj0.w;
                        a1[i] += q.x * kj1.x + q.y * kj1.y + q.z * kj1.z + q.w * kj1.w;
                    }
                }
#pragma unroll
                for (int i = 0; i < 7; i++) {
                    LtT[jp * 2][ig * 7 + i]     = w * fmaxf(0.f, -SCL * a0[i]);
                    LtT[jp * 2 + 1][ig * 7 + i] = w * fmaxf(0.f, -SCL * a1[i]);
                }
            } else if (t < 392) {
                // R: 28x196, 2 rows x 14 cols per thread (14 j-pairs x 14 k-groups)
                const int tt = t - 196;
                const int jp = tt / 14, kg = tt % 14;
                float a0[14], a1[14];
#pragma unroll
                for (int k = 0; k < 14; k++) { a0[k] = 0.f; a1[k] = 0.f; }
                for (int d4 = 0; d4 < 64; d4 += 4) {
                    const float4 c0v = *(const float4*)&k2s[jp * 2][d4];
                    const float4 c1v = *(const float4*)&k2s[jp * 2 + 1][d4];
#pragma unroll
                    for (int k = 0; k < 14; k++) {
                        const float4 q = *(const float4*)&q2s[kg * 14 + k][d4];
                        a0[k] += c0v.x * q.x + c0v.y * q.y + c0v.z * q.z + c0v.w * q.w;
                        a1[k] += c1v.x * q.x + c1v.y * q.y + c1v.z * q.z + c1v.w * q.w;
                    }
                }
#pragma unroll
                for (int k = 0; k < 14; k++) {
                    Rt[jp * 2][kg * 14 + k]     = fmaxf(0.f, SCL * a0[k]);
                    Rt[jp * 2 + 1][kg * 14 + k] = fmaxf(0.f, SCL * a1[k]);
                }
            }
            __syncthreads();
            if (t < 392) {
                const int tr = t / 28, tc = t % 28;
#pragma unroll 4
                for (int kk = 0; kk < 28; kk++) {
                    float lt[7], rt[7];
#pragma unroll
                    for (int i = 0; i < 7; i++) lt[i] = LtT[kk][tr * 7 + i];
#pragma unroll
                    for (int j = 0; j < 7; j++) rt[j] = Rt[kk][tc * 7 + j];
#pragma unroll
                    for (int i = 0; i < 7; i++)
#pragma unroll
                        for (int j = 0; j < 7; j++) acc[i][j] += lt[i] * rt[j];
                }
            }
        }
    }

    if (t < 392) {
        const int tr = t / 28, tc = t % 28;
        float* tp = (cg == 0) ? tmp0 : tmp1;
#pragma unroll
        for (int i = 0; i < 7; i++) {
            const size_t base = ((size_t)((b * 6 + h) * 196 + n0 + tr * 7 + i)) * 196 + tc * 7;
#pragma unroll
            for (int j = 0; j < 7; j++) tp[base + j] = acc[i][j];
        }
    }
}

// ---------------------------------------------------------------------------
// rect_pre[b,h,n,d] = sum_k (tmp0+tmp1)[b,h,n,k] * VR[b*196+k, h*64+d]
// *** Stored CONTIGUOUS in (b,h,n,d) order *** because the reference does
// rect.reshape(B,N,C) on the (B,H,N,HD) tensor WITHOUT transposing — the
// (h,n,d) flat order IS the reshaped (n',c') layout. (Round-1 bug: wrote
// the transposed (b,n,h*64+d) layout -> absmax 12.8.)
// Grid (7,6,16), 256 threads: 4 row-groups x 64 d-lanes, 7 rows each.
// ---------------------------------------------------------------------------
__global__ void rect_pre_kernel(const float* __restrict__ tmp0, const float* __restrict__ tmp1,
                                const float* __restrict__ VR, float* __restrict__ rect_pre) {
    const int b = blockIdx.z, h = blockIdx.y, n0 = blockIdx.x * 28;
    const int t = threadIdx.x;
    const int tr = t >> 6, d = t & 63;
    float acc[7];
#pragma unroll
    for (int i = 0; i < 7; i++) acc[i] = 0.f;
    const size_t tb = (size_t)((b * 6 + h) * 196) * 196;
    for (int k = 0; k < 196; k++) {
        const float vv = VR[(size_t)(b * 196 + k) * 384 + h * 64 + d];
#pragma unroll
        for (int i = 0; i < 7; i++) {
            const size_t idx = tb + (size_t)(n0 + tr * 7 + i) * 196 + k;
            acc[i] += (tmp0[idx] + tmp1[idx]) * vv;
        }
    }
#pragma unroll
    for (int i = 0; i < 7; i++)
        rect_pre[((size_t)((b * 6 + h) * 196 + n0 + tr * 7 + i)) * 64 + d] = acc[i];
}

// ---------------------------------------------------------------------------
// Copy anchors (last 10 batches) input -> output, verbatim.
// ---------------------------------------------------------------------------
__global__ void copy_anchors(const float* __restrict__ x, float* __restrict__ out) {
    const int e = blockIdx.x * 256 + threadIdx.x;
    if (e < 189120) {   // 10*197*384/4
        const int base = 16 * 197 * 384 / 4;
        ((float4*)out)[base + e] = ((const float4*)x)[base + e];
    }
}

// ---------------------------------------------------------------------------
// kernel_launch.  Workspace layout (floats), total 14,481,600 f = 58 MB,
// with phase-ordered aliasing (rect_pre@QH, xx/hdn@tmp1, G@Q2).
// ---------------------------------------------------------------------------
extern "C" void kernel_launch(void* const* d_in, const int* in_sizes, int n_in,
                              void* d_out, int out_size, void* d_ws, size_t ws_size,
                              hipStream_t stream) {
    (void)in_sizes; (void)n_in; (void)out_size; (void)ws_size;
    const float* x       = (const float*)d_in[0];
    const float* Wqv     = (const float*)d_in[1];
    const float* Wk      = (const float*)d_in[2];
    const float* Wq_proj = (const float*)d_in[3];
    const float* bq_proj = (const float*)d_in[4];
    const float* Wqk     = (const float*)d_in[5];
    const float* Wqk2    = (const float*)d_in[6];
    const float* Wv      = (const float*)d_in[7];
    const float* Wr_proj = (const float*)d_in[8];
    const float* br_proj = (const float*)d_in[9];
    const float* g1      = (const float*)d_in[10];
    const float* b1      = (const float*)d_in[11];
    const float* g2      = (const float*)d_in[12];
    const float* b2      = (const float*)d_in[13];
    const float* g3      = (const float*)d_in[14];
    const float* b3      = (const float*)d_in[15];
    const float* W1      = (const float*)d_in[16];
    const float* bm1     = (const float*)d_in[17];
    const float* W2      = (const float*)d_in[18];
    const float* bm2     = (const float*)d_in[19];

    float* ws = (float*)d_ws;
    float* n1       = ws;               //     9,984
    float* qv       = ws + 9984;        //     7,680
    float* kcls     = ws + 17664;       //     6,144
    float* aflat    = ws + 23808;       //       960
    float* cls_pre  = ws + 24768;       //     6,144
    float* n2x      = ws + 30912;       // 1,204,224
    float* n2a      = ws + 1235136;     //   752,640
    float* QH       = ws + 1987776;     // 1,204,224  (dead after chain)
    float* Q2       = ws + 3192000;     // 1,204,224  (dead after chain)
    float* VR       = ws + 4396224;     // 1,204,224  (dead after rect_pre)
    float* KH       = ws + 5600448;     //   752,640  (dead after chain)
    float* K2       = ws + 6353088;     //   752,640  (dead after chain)
    float* tmp0     = ws + 7105728;     // 3,687,936  (dead after rect_pre)
    float* tmp1     = ws + 10793664;    // 3,687,936  (dead after rect_pre)
    float* rect_pre = QH;               // alias: written in phase 8
    float* xx       = tmp1;             // alias: written after rect_pre reads tmp1
    float* hdn      = tmp1 + 1210368;   // alias within tmp1 region
    float* G        = Q2;               // alias: MLP hidden (4.84M f spans Q2..tmp0 head)
    float* outf     = (float*)d_out;

    // 1. LN of cls tokens (16 xs + 10 anchors)
    ln_kernel<<<26, 64, 0, stream>>>(x, n1, g1, b1, 0);
    // 2. qv = n1a @ Wqv (10x768) ; kcls = n1x @ Wk (16x384)
    gemm_small<<<30, 256, 0, stream>>>(n1 + 16 * 384, Wqv, nullptr, qv, 10, 768, 384, 768);
    gemm_small<<<24, 256, 0, stream>>>(n1, Wk, nullptr, kcls, 16, 384, 384, 384);
    // 3. cls attention -> aflat (softmax probs), cls_pre
    attn_cls_kernel<<<16, 64, 0, stream>>>(qv, kcls, aflat, cls_pre);
    // 5. LN of image tokens
    ln_kernel<<<3136, 64, 0, stream>>>(x, n2x, g2, b2, 1);
    ln_kernel<<<1960, 64, 0, stream>>>(x, n2a, g2, b2, 2);
    // 6. head projections (no bias)
    dim3 gx(3, 25), ga(3, 16);
    gemm128<0, false><<<gx, 256, 0, stream>>>(n2x, Wqk,  nullptr, nullptr, QH, 3136, 384, 384);
    gemm128<0, false><<<gx, 256, 0, stream>>>(n2x, Wqk2, nullptr, nullptr, Q2, 3136, 384, 384);
    gemm128<0, false><<<gx, 256, 0, stream>>>(n2x, Wv,   nullptr, nullptr, VR, 3136, 384, 384);
    gemm128<0, false><<<ga, 256, 0, stream>>>(n2a, Wqk,  nullptr, nullptr, KH, 1960, 384, 384);
    gemm128<0, false><<<ga, 256, 0, stream>>>(n2a, Wqk2, nullptr, nullptr, K2, 1960, 384, 384);
    // 7. rectified-attention chain -> tmp0 (c 0..4), tmp1 (c 5..9)
    chain_kernel<<<dim3(4, 6, 16), 512, 0, stream>>>(QH, KH, Q2, K2, aflat, tmp0, tmp1);
    // 8. rect_pre = (tmp0+tmp1) @ vr  (per b,h; contiguous (b,h,n,d) = reshape layout)
    rect_pre_kernel<<<dim3(7, 6, 16), 256, 0, stream>>>(tmp0, tmp1, VR, rect_pre);
    // 4'. cls_out -> xx token 0 (after tmp1 is dead; xx aliases tmp1)
    gemm_small<<<24, 256, 0, stream>>>(cls_pre, Wq_proj, bq_proj, xx, 16, 384, 384, 197 * 384);
    // 9. xx[:,1:] = rect_pre @ Wr_proj + br + x_im   (row-remapped residual+store)
    gemm128<0, true><<<gx, 256, 0, stream>>>(rect_pre, Wr_proj, br_proj, x, xx, 3136, 384, 384);
    // 10. LN3 over all 3152 xx rows
    ln_kernel<<<3152, 64, 0, stream>>>(xx, hdn, g3, b3, 3);
    // 11. MLP up + exact GELU
    gemm128<1, false><<<dim3(12, 25), 256, 0, stream>>>(hdn, W1, bm1, nullptr, G, 3152, 1536, 384);
    // 12. MLP down + bias + residual -> out rows 0..3151
    gemm128<0, false><<<dim3(3, 25), 256, 0, stream>>>(G, W2, bm2, xx, outf, 3152, 384, 1536);
    // 13. anchors pass-through
    copy_anchors<<<739, 256, 0, stream>>>(x, outf);
}

// Round 3
// 1234.889 us; speedup vs baseline: 1.7559x; 1.7559x over previous
//
#include <hip/hip_runtime.h>
#include <hip/hip_bf16.h>
#include <math.h>

#define SCL 0.125f

typedef float f32x4 __attribute__((ext_vector_type(4)));
typedef short bf16x8 __attribute__((ext_vector_type(8)));   // 8 bf16 in 4 VGPRs
#define MFMA16(a, b, c) __builtin_amdgcn_mfma_f32_16x16x32_bf16((a), (b), (c), 0, 0, 0)

// f32 -> bf16 with round-to-nearest-even
__device__ __forceinline__ unsigned short f2bf(float f) {
    unsigned int u = __builtin_bit_cast(unsigned int, f);
    u = (u + 0x7FFFu + ((u >> 16) & 1u)) >> 16;
    return (unsigned short)u;
}

// ---------------------------------------------------------------------------
// LayerNorm over last dim (384). One wave per row. Modes as before.
// ---------------------------------------------------------------------------
__global__ void ln_kernel(const float* __restrict__ x, float* __restrict__ out,
                          const float* __restrict__ g, const float* __restrict__ bt,
                          int mode) {
    const int row = blockIdx.x;
    const int lane = threadIdx.x;           // 64 threads
    const float* src;
    if (mode == 0)      src = x + (size_t)row * (197 * 384);
    else if (mode == 1) { int b = row / 196, n = row % 196; src = x + (size_t)(b * 197 + 1 + n) * 384; }
    else if (mode == 2) { int b = row / 196, n = row % 196; src = x + (size_t)((16 + b) * 197 + 1 + n) * 384; }
    else                src = x + (size_t)row * 384;

    float v[6];
    float s = 0.f, s2 = 0.f;
#pragma unroll
    for (int j = 0; j < 6; j++) {
        v[j] = src[lane + j * 64];
        s += v[j];
        s2 += v[j] * v[j];
    }
#pragma unroll
    for (int o = 32; o; o >>= 1) {
        s  += __shfl_xor(s, o);
        s2 += __shfl_xor(s2, o);
    }
    const float mu = s * (1.f / 384.f);
    const float var = s2 * (1.f / 384.f) - mu * mu;
    const float rs = 1.f / sqrtf(var + 1e-5f);
    float* dst = out + (size_t)row * 384;
#pragma unroll
    for (int j = 0; j < 6; j++) {
        const int c = lane + j * 64;
        dst[c] = (v[j] - mu) * rs * g[c] + bt[c];
    }
}

// ---------------------------------------------------------------------------
// Tiny GEMM (cls path, M<=16)
// ---------------------------------------------------------------------------
__global__ void gemm_small(const float* __restrict__ A, const float* __restrict__ B,
                           const float* __restrict__ bias, float* __restrict__ C,
                           int M, int N, int K, int ldc) {
    const int e = blockIdx.x * 256 + threadIdx.x;
    if (e >= M * N) return;
    const int m = e / N, n = e % N;
    float acc = bias ? bias[n] : 0.f;
    const float* a = A + (size_t)m * K;
    for (int k = 0; k < K; k++) acc += a[k] * B[(size_t)k * N + n];
    C[(size_t)m * ldc + n] = acc;
}

// ---------------------------------------------------------------------------
// cls attention (unchanged, verified)
// ---------------------------------------------------------------------------
__global__ void attn_cls_kernel(const float* __restrict__ qv, const float* __restrict__ kcls,
                                float* __restrict__ aflat, float* __restrict__ cls_pre) {
    const int b = blockIdx.x;
    const int t = threadIdx.x;  // 64
    __shared__ float kb[384];
    __shared__ float pl[60];
#pragma unroll
    for (int j = 0; j < 6; j++) kb[t + j * 64] = kcls[b * 384 + t + j * 64];
    __syncthreads();
    if (t < 60) {
        const int n = t / 6, h = t % 6;
        float acc = 0.f;
        for (int d = 0; d < 64; d++) acc += qv[n * 768 + h * 64 + d] * kb[h * 64 + d];
        pl[t] = acc * SCL;
    }
    __syncthreads();
    if (t < 6) {
        float m = -1e30f;
        for (int n = 0; n < 10; n++) m = fmaxf(m, pl[n * 6 + t]);
        float p[10], sum = 0.f;
        for (int n = 0; n < 10; n++) { p[n] = expf(pl[n * 6 + t] - m); sum += p[n]; }
        const float inv = 1.f / sum;
        for (int n = 0; n < 10; n++) {
            const float pr = p[n] * inv;
            pl[n * 6 + t] = pr;
            aflat[b * 60 + n * 6 + t] = pr;   // reference flat (n,h) order
        }
    }
    __syncthreads();
#pragma unroll
    for (int j = 0; j < 6; j++) {
        const int c = t + j * 64;
        const int h = c >> 6;
        float acc = 0.f;
        for (int n = 0; n < 10; n++) acc += pl[n * 6 + h] * qv[n * 768 + 384 + c];
        cls_pre[b * 384 + c] = acc;
    }
}

// ---------------------------------------------------------------------------
// Tiled fp32 GEMM. BF16OUT=1: write bf16 row-major [row][N] (no bias/act/res).
// ---------------------------------------------------------------------------
__device__ __forceinline__ float gelu_exact(float v) {
    return 0.5f * v * (1.f + erff(v * 0.70710678118654752f));
}

template <int ACT, bool REMAP, int BF16OUT>
__launch_bounds__(256)
__global__ void gemm128(const float* __restrict__ A, const float* __restrict__ Bm,
                        const float* __restrict__ bias, const float* __restrict__ res,
                        float* __restrict__ C, int M, int N, int K) {
    __shared__ float As[8][132];
    __shared__ float Bs[8][132];
    const int n0 = blockIdx.x * 128, m0 = blockIdx.y * 128;
    const int t = threadIdx.x;
    const int tx = t & 15, ty = t >> 4;
    float acc[8][8];
#pragma unroll
    for (int i = 0; i < 8; i++)
#pragma unroll
        for (int j = 0; j < 8; j++) acc[i][j] = 0.f;

    const int am = t >> 1, akq = (t & 1) * 4;
    const int bkk = t >> 5, bnq = (t & 31) * 4;

    for (int k0 = 0; k0 < K; k0 += 8) {
        float4 f = make_float4(0.f, 0.f, 0.f, 0.f);
        const int arow = m0 + am;
        if (arow < M) f = *(const float4*)(A + (size_t)arow * K + k0 + akq);
        As[akq][am] = f.x; As[akq + 1][am] = f.y; As[akq + 2][am] = f.z; As[akq + 3][am] = f.w;
        const float4 gq = *(const float4*)(Bm + (size_t)(k0 + bkk) * N + n0 + bnq);
        *(float4*)&Bs[bkk][bnq] = gq;
        __syncthreads();
#pragma unroll
        for (int kk = 0; kk < 8; kk++) {
            float a[8], bb[8];
            *(float4*)&a[0]  = *(float4*)&As[kk][ty * 8];
            *(float4*)&a[4]  = *(float4*)&As[kk][ty * 8 + 4];
            *(float4*)&bb[0] = *(float4*)&Bs[kk][tx * 8];
            *(float4*)&bb[4] = *(float4*)&Bs[kk][tx * 8 + 4];
#pragma unroll
            for (int i = 0; i < 8; i++)
#pragma unroll
                for (int j = 0; j < 8; j++) acc[i][j] += a[i] * bb[j];
        }
        __syncthreads();
    }

#pragma unroll
    for (int i = 0; i < 8; i++) {
        const int row = m0 + ty * 8 + i;
        if (row >= M) break;
        const int crow = REMAP ? (row + row / 196 + 1) : row;
        if (BF16OUT) {
            unsigned short p[8];
#pragma unroll
            for (int j = 0; j < 8; j++) p[j] = f2bf(acc[i][j]);
            unsigned short* Cb = (unsigned short*)C;
            *(uint4*)&Cb[(size_t)crow * N + n0 + tx * 8] = *(uint4*)p;
        } else {
#pragma unroll
            for (int j = 0; j < 8; j += 4) {
                const int col = n0 + tx * 8 + j;
                float4 v;
                v.x = acc[i][j]; v.y = acc[i][j + 1]; v.z = acc[i][j + 2]; v.w = acc[i][j + 3];
                if (bias) {
                    v.x += bias[col]; v.y += bias[col + 1]; v.z += bias[col + 2]; v.w += bias[col + 3];
                }
                if (ACT == 1) {
                    v.x = gelu_exact(v.x); v.y = gelu_exact(v.y);
                    v.z = gelu_exact(v.z); v.w = gelu_exact(v.w);
                }
                if (res) {
                    const float4 r = *(const float4*)(res + (size_t)crow * N + col);
                    v.x += r.x; v.y += r.y; v.z += r.z; v.w += r.w;
                }
                *(float4*)(C + (size_t)crow * N + col) = v;
            }
        }
    }
}

// ===========================================================================
// MFMA chain, stage A:  Zt[b,h,c][d][m] = sum_k relu(SCL*k2_c[m]·q2_b[k]) * vr_b[k,d]
// One block per (c,h,b). 256 threads (4 waves). All tiles 16x16x32 bf16 MFMA.
// Tile geometry: m,k padded 196->208 (13 tiles); contraction k padded to 224
// (7 chunks of 32), pad regions zeroed. LDS strides 72/232 bf16 (bank spread).
// ===========================================================================
__global__ __launch_bounds__(256, 1)
void rz_kernel(const unsigned short* __restrict__ Q2b, const unsigned short* __restrict__ K2b,
               const unsigned short* __restrict__ VRb, unsigned short* __restrict__ Zt) {
    const int c = blockIdx.x, h = blockIdx.y, b = blockIdx.z;
    const int t = threadIdx.x;
    const int w = t >> 6, l = t & 63;
    const int lr = l & 15;      // row/col-within-tile selector
    const int lk = l >> 4;      // k-subchunk (0..3)

    __shared__ unsigned short sm[78208];          // 156,416 B
    unsigned short* sQ2 = sm;                     // [208][72]  (29,952 B)
    unsigned short* sVT = sm;                     // [64][232]  alias, phase 2+
    unsigned short* sK2 = sm + 14976;             // [208][72]
    unsigned short* sR  = sm + 29952;             // [208][232] (96,512 B)

    // phase 0: stage q2, k2 (zero rows 196..207); zero sR cols 208..223
    const unsigned short* q2src = Q2b + ((size_t)(b * 196)) * 384 + h * 64;
    const unsigned short* k2src = K2b + ((size_t)(c * 196)) * 384 + h * 64;
    for (int e = t; e < 208 * 8; e += 256) {
        const int r = e >> 3, ch = e & 7;
        uint4 v = make_uint4(0, 0, 0, 0);
        if (r < 196) v = *(const uint4*)(q2src + (size_t)r * 384 + ch * 8);
        *(uint4*)&sQ2[r * 72 + ch * 8] = v;
    }
    for (int e = t; e < 208 * 8; e += 256) {
        const int r = e >> 3, ch = e & 7;
        uint4 v = make_uint4(0, 0, 0, 0);
        if (r < 196) v = *(const uint4*)(k2src + (size_t)r * 384 + ch * 8);
        *(uint4*)&sK2[r * 72 + ch * 8] = v;
    }
    for (int e = t; e < 208 * 16; e += 256) sR[(e >> 4) * 232 + 208 + (e & 15)] = 0;
    __syncthreads();

    // phase 1: S = k2 @ q2^T (13x13 tiles, K=64=2 chunks); R = relu(SCL*S) -> sR
    for (int tt = w; tt < 169; tt += 4) {
        const int mt = tt / 13, kt = tt % 13;
        f32x4 acc = {0.f, 0.f, 0.f, 0.f};
        bf16x8 a0 = *(const bf16x8*)&sK2[(mt * 16 + lr) * 72 + lk * 8];
        bf16x8 b0 = *(const bf16x8*)&sQ2[(kt * 16 + lr) * 72 + lk * 8];
        acc = MFMA16(a0, b0, acc);
        bf16x8 a1 = *(const bf16x8*)&sK2[(mt * 16 + lr) * 72 + 32 + lk * 8];
        bf16x8 b1 = *(const bf16x8*)&sQ2[(kt * 16 + lr) * 72 + 32 + lk * 8];
        acc = MFMA16(a1, b1, acc);
        const int rrow = mt * 16 + lk * 4, rcol = kt * 16 + lr;
#pragma unroll
        for (int i = 0; i < 4; i++)
            sR[(rrow + i) * 232 + rcol] = f2bf(fmaxf(0.f, SCL * acc[i]));
    }
    __syncthreads();

    // phase 2: stage vr transposed into sVT[d][k] (overwrites q2 region); zero pad cols
    const unsigned short* vrsrc = VRb + ((size_t)(b * 196)) * 384 + h * 64;
    for (int e = t; e < 196 * 8; e += 256) {
        const int kk = e >> 3, ch = e & 7;
        uint4 v = *(const uint4*)(vrsrc + (size_t)kk * 384 + ch * 8);
        unsigned short vs[8]; *(uint4*)vs = v;
#pragma unroll
        for (int j = 0; j < 8; j++) sVT[(ch * 8 + j) * 232 + kk] = vs[j];
    }
    for (int e = t; e < 64 * 36; e += 256) sVT[(e / 36) * 232 + 196 + (e % 36)] = 0;
    __syncthreads();

    // phase 3: Z = R @ vr (13 m-tiles x 4 d-tiles, K=224=7 chunks) -> Zt[d][m] bf16
    unsigned short* zdst = Zt + ((((size_t)(b * 6 + h)) * 10 + c) * 64) * 208;
    for (int tt = w; tt < 52; tt += 4) {
        const int mt = tt >> 2, dt = tt & 3;
        f32x4 acc = {0.f, 0.f, 0.f, 0.f};
#pragma unroll
        for (int kc = 0; kc < 7; kc++) {
            bf16x8 a = *(const bf16x8*)&sR[(mt * 16 + lr) * 232 + kc * 32 + lk * 8];
            bf16x8 bb = *(const bf16x8*)&sVT[(dt * 16 + lr) * 232 + kc * 32 + lk * 8];
            acc = MFMA16(a, bb, acc);
        }
        unsigned short p[4];
#pragma unroll
        for (int i = 0; i < 4; i++) p[i] = f2bf(acc[i]);
        *(uint2*)&zdst[(size_t)(dt * 16 + lr) * 208 + mt * 16 + lk * 4] = *(uint2*)p;
    }
}

// ===========================================================================
// MFMA chain, stage B:
//   rect_pre[b,h,n,d] = sum_c  (w_c * relu(-SCL*qh_b[n]·kh_c[m])) @ Zt[b,h,c]
// One block per (n-half, h, b) = 192 blocks, 256 threads. Wave w owns d-tile w.
// ===========================================================================
__global__ __launch_bounds__(256, 1)
void yz_kernel(const unsigned short* __restrict__ QHb, const unsigned short* __restrict__ KHb,
               const unsigned short* __restrict__ Zt, const float* __restrict__ aflat,
               float* __restrict__ rect) {
    const int ns = blockIdx.x, h = blockIdx.y, b = blockIdx.z;
    const int n0 = ns * 98;
    const int t = threadIdx.x;
    const int w = t >> 6, l = t & 63;
    const int lr = l & 15, lk = l >> 4;

    __shared__ unsigned short sQH[112 * 72];   // 16,128 B (rows 98..111 zero)
    __shared__ unsigned short sKH[208 * 72];   // 29,952 B (rows 196..207 zero)
    __shared__ unsigned short sZT[64 * 232];   // 29,696 B (cols 208..231 zero)
    __shared__ unsigned short sL[112 * 232];   // 51,968 B (cols 208..223 zero)

    for (int e = t; e < 112 * 8; e += 256) {
        const int r = e >> 3, ch = e & 7;
        uint4 v = make_uint4(0, 0, 0, 0);
        if (r < 98) v = *(const uint4*)(QHb + ((size_t)(b * 196 + n0 + r)) * 384 + h * 64 + ch * 8);
        *(uint4*)&sQH[r * 72 + ch * 8] = v;
    }
    for (int e = t; e < 112 * 16; e += 256) sL[(e >> 4) * 232 + 208 + (e & 15)] = 0;
    for (int e = t; e < 64 * 24; e += 256) sZT[(e / 24) * 232 + 208 + (e % 24)] = 0;

    f32x4 y[7];
#pragma unroll
    for (int i = 0; i < 7; i++) y[i] = (f32x4){0.f, 0.f, 0.f, 0.f};

    for (int c = 0; c < 10; c++) {
        __syncthreads();    // previous iter's MFMA reads done before restage
        for (int e = t; e < 208 * 8; e += 256) {
            const int r = e >> 3, ch = e & 7;
            uint4 v = make_uint4(0, 0, 0, 0);
            if (r < 196) v = *(const uint4*)(KHb + ((size_t)(c * 196 + r)) * 384 + h * 64 + ch * 8);
            *(uint4*)&sKH[r * 72 + ch * 8] = v;
        }
        const unsigned short* zsrc = Zt + ((((size_t)(b * 6 + h)) * 10 + c) * 64) * 208;
        for (int e = t; e < 64 * 26; e += 256) {
            const int d = e / 26, mc = e % 26;
            uint4 v = *(const uint4*)(zsrc + (size_t)d * 208 + mc * 8);
            *(uint4*)&sZT[d * 232 + mc * 8] = v;
        }
        const float wc = aflat[b * 60 + h * 10 + c];
        __syncthreads();
        // L = wc * relu(-SCL * qh @ kh^T): 7 n-tiles x 13 m-tiles
        for (int tt = w; tt < 91; tt += 4) {
            const int nt = tt / 13, mt = tt % 13;
            f32x4 acc = {0.f, 0.f, 0.f, 0.f};
            bf16x8 a0 = *(const bf16x8*)&sQH[(nt * 16 + lr) * 72 + lk * 8];
            bf16x8 b0 = *(const bf16x8*)&sKH[(mt * 16 + lr) * 72 + lk * 8];
            acc = MFMA16(a0, b0, acc);
            bf16x8 a1 = *(const bf16x8*)&sQH[(nt * 16 + lr) * 72 + 32 + lk * 8];
            bf16x8 b1 = *(const bf16x8*)&sKH[(mt * 16 + lr) * 72 + 32 + lk * 8];
            acc = MFMA16(a1, b1, acc);
            const int lrow = nt * 16 + lk * 4, lcol = mt * 16 + lr;
#pragma unroll
            for (int i = 0; i < 4; i++)
                sL[(lrow + i) * 232 + lcol] = f2bf(wc * fmaxf(0.f, -SCL * acc[i]));
        }
        __syncthreads();
        // Y += L @ Z: wave w owns d-tile w; 7 n-tiles; K=224 (7 chunks)
#pragma unroll
        for (int nt = 0; nt < 7; nt++) {
            f32x4 acc = y[nt];
#pragma unroll
            for (int mc = 0; mc < 7; mc++) {
                bf16x8 a  = *(const bf16x8*)&sL[(nt * 16 + lr) * 232 + mc * 32 + lk * 8];
                bf16x8 bb = *(const bf16x8*)&sZT[(w * 16 + lr) * 232 + mc * 32 + lk * 8];
                acc = MFMA16(a, bb, acc);
            }
            y[nt] = acc;
        }
    }

    // write rect_pre fp32, layout ((b*6+h)*196 + n)*64 + d  (verified reshape order)
#pragma unroll
    for (int nt = 0; nt < 7; nt++) {
#pragma unroll
        for (int i = 0; i < 4; i++) {
            const int n = nt * 16 + lk * 4 + i;
            if (n < 98)
                rect[(((size_t)(b * 6 + h)) * 196 + n0 + n) * 64 + w * 16 + lr] = y[nt][i];
        }
    }
}

// ---------------------------------------------------------------------------
// Copy anchors (last 10 batches) input -> output, verbatim.
// ---------------------------------------------------------------------------
__global__ void copy_anchors(const float* __restrict__ x, float* __restrict__ out) {
    const int e = blockIdx.x * 256 + threadIdx.x;
    if (e < 189120) {
        const int base = 16 * 197 * 384 / 4;
        ((float4*)out)[base + e] = ((const float4*)x)[base + e];
    }
}

// ---------------------------------------------------------------------------
// kernel_launch. Workspace (f32 units, total 10,936,512 f = 43.7 MB):
//  aliases: rect_pre@n2x, xx@[Q2b..K2b], hdn+G inside Zt region.
// ---------------------------------------------------------------------------
extern "C" void kernel_launch(void* const* d_in, const int* in_sizes, int n_in,
                              void* d_out, int out_size, void* d_ws, size_t ws_size,
                              hipStream_t stream) {
    (void)in_sizes; (void)n_in; (void)out_size; (void)ws_size;
    const float* x       = (const float*)d_in[0];
    const float* Wqv     = (const float*)d_in[1];
    const float* Wk      = (const float*)d_in[2];
    const float* Wq_proj = (const float*)d_in[3];
    const float* bq_proj = (const float*)d_in[4];
    const float* Wqk     = (const float*)d_in[5];
    const float* Wqk2    = (const float*)d_in[6];
    const float* Wv      = (const float*)d_in[7];
    const float* Wr_proj = (const float*)d_in[8];
    const float* br_proj = (const float*)d_in[9];
    const float* g1      = (const float*)d_in[10];
    const float* b1      = (const float*)d_in[11];
    const float* g2      = (const float*)d_in[12];
    const float* b2      = (const float*)d_in[13];
    const float* g3      = (const float*)d_in[14];
    const float* b3      = (const float*)d_in[15];
    const float* W1      = (const float*)d_in[16];
    const float* bm1     = (const float*)d_in[17];
    const float* W2      = (const float*)d_in[18];
    const float* bm2     = (const float*)d_in[19];

    float* ws = (float*)d_ws;
    float* n1       = ws;               //      9,984
    float* qv       = ws + 9984;        //      7,680
    float* kcls     = ws + 17664;       //      6,144
    float* aflat    = ws + 23808;       //        960
    float* cls_pre  = ws + 24768;       //      6,144
    float* n2x      = ws + 30912;       //  1,204,224   [-> rect_pre]
    float* n2a      = ws + 1235136;     //    752,640
    unsigned short* QHb = (unsigned short*)(ws + 1987776);  // 3136x384 bf16
    unsigned short* Q2b = (unsigned short*)(ws + 2589888);  // 3136x384 bf16
    unsigned short* VRb = (unsigned short*)(ws + 3192000);  // 3136x384 bf16
    unsigned short* K2b = (unsigned short*)(ws + 3794112);  // 1960x384 bf16
    unsigned short* KHb = (unsigned short*)(ws + 4170432);  // 1960x384 bf16
    unsigned short* Zt  = (unsigned short*)(ws + 4546752);  // 96*10*64*208 bf16
    float* rect_pre = n2x;              // alias (n2x dead after projections)
    float* xx       = ws + 2589888;     // alias over Q2b..K2b (dead after chain)
    float* hdn      = ws + 4546752;     // alias in Zt region (Zt dead after yz)
    float* G        = ws + 5757120;     // alias in Zt region, 3152x1536
    float* outf     = (float*)d_out;

    // 1. LN cls tokens
    ln_kernel<<<26, 64, 0, stream>>>(x, n1, g1, b1, 0);
    // 2. qv / kcls
    gemm_small<<<30, 256, 0, stream>>>(n1 + 16 * 384, Wqv, nullptr, qv, 10, 768, 384, 768);
    gemm_small<<<24, 256, 0, stream>>>(n1, Wk, nullptr, kcls, 16, 384, 384, 384);
    // 3. cls attention
    attn_cls_kernel<<<16, 64, 0, stream>>>(qv, kcls, aflat, cls_pre);
    // 4. LN image tokens
    ln_kernel<<<3136, 64, 0, stream>>>(x, n2x, g2, b2, 1);
    ln_kernel<<<1960, 64, 0, stream>>>(x, n2a, g2, b2, 2);
    // 5. head projections -> bf16
    dim3 gx(3, 25), ga(3, 16);
    gemm128<0, false, 1><<<gx, 256, 0, stream>>>(n2x, Wqk,  nullptr, nullptr, (float*)QHb, 3136, 384, 384);
    gemm128<0, false, 1><<<gx, 256, 0, stream>>>(n2x, Wqk2, nullptr, nullptr, (float*)Q2b, 3136, 384, 384);
    gemm128<0, false, 1><<<gx, 256, 0, stream>>>(n2x, Wv,   nullptr, nullptr, (float*)VRb, 3136, 384, 384);
    gemm128<0, false, 1><<<ga, 256, 0, stream>>>(n2a, Wqk,  nullptr, nullptr, (float*)KHb, 1960, 384, 384);
    gemm128<0, false, 1><<<ga, 256, 0, stream>>>(n2a, Wqk2, nullptr, nullptr, (float*)K2b, 1960, 384, 384);
    // 6. chain stage A: Zt = relu(SCL*k2@q2^T) @ vr   (per b,h,c)
    rz_kernel<<<dim3(10, 6, 16), 256, 0, stream>>>(Q2b, K2b, VRb, Zt);
    // 7. chain stage B: rect_pre = sum_c (wc*relu(-SCL*qh@kh^T)) @ Zt
    yz_kernel<<<dim3(2, 6, 16), 256, 0, stream>>>(QHb, KHb, Zt, aflat, rect_pre);
    // 8. cls_out -> xx token 0
    gemm_small<<<24, 256, 0, stream>>>(cls_pre, Wq_proj, bq_proj, xx, 16, 384, 384, 197 * 384);
    // 9. xx[:,1:] = rect_pre @ Wr_proj + br + x_im
    gemm128<0, true, 0><<<gx, 256, 0, stream>>>(rect_pre, Wr_proj, br_proj, x, xx, 3136, 384, 384);
    // 10. LN3
    ln_kernel<<<3152, 64, 0, stream>>>(xx, hdn, g3, b3, 3);
    // 11. MLP up + GELU
    gemm128<1, false, 0><<<dim3(12, 25), 256, 0, stream>>>(hdn, W1, bm1, nullptr, G, 3152, 1536, 384);
    // 12. MLP down + bias + residual -> out
    gemm128<0, false, 0><<<dim3(3, 25), 256, 0, stream>>>(G, W2, bm2, xx, outf, 3152, 384, 1536);
    // 13. anchors pass-through
    copy_anchors<<<739, 256, 0, stream>>>(x, outf);
}

// Round 4
// 762.913 us; speedup vs baseline: 2.8423x; 1.6187x over previous
//
#include <hip/hip_runtime.h>
#include <hip/hip_bf16.h>
#include <math.h>

#define SCL 0.125f

typedef float f32x4 __attribute__((ext_vector_type(4)));
typedef short bf16x8 __attribute__((ext_vector_type(8)));   // 8 bf16 in 4 VGPRs
#define MFMA16(a, b, c) __builtin_amdgcn_mfma_f32_16x16x32_bf16((a), (b), (c), 0, 0, 0)

// f32 -> bf16 round-to-nearest-even
__device__ __forceinline__ unsigned short f2bf(float f) {
    unsigned int u = __builtin_bit_cast(unsigned int, f);
    u = (u + 0x7FFFu + ((u >> 16) & 1u)) >> 16;
    return (unsigned short)u;
}

__device__ __forceinline__ float gelu_exact(float v) {
    return 0.5f * v * (1.f + erff(v * 0.70710678118654752f));
}

// ---------------------------------------------------------------------------
// LayerNorm over last dim (384). One wave per row. BF16OUT picks dst type.
// ---------------------------------------------------------------------------
template <int BF16OUT>
__global__ void ln_kernel(const float* __restrict__ x, void* __restrict__ outp,
                          const float* __restrict__ g, const float* __restrict__ bt,
                          int mode) {
    const int row = blockIdx.x;
    const int lane = threadIdx.x;           // 64 threads
    const float* src;
    if (mode == 0)      src = x + (size_t)row * (197 * 384);
    else if (mode == 1) { int b = row / 196, n = row % 196; src = x + (size_t)(b * 197 + 1 + n) * 384; }
    else if (mode == 2) { int b = row / 196, n = row % 196; src = x + (size_t)((16 + b) * 197 + 1 + n) * 384; }
    else                src = x + (size_t)row * 384;

    float v[6];
    float s = 0.f, s2 = 0.f;
#pragma unroll
    for (int j = 0; j < 6; j++) {
        v[j] = src[lane + j * 64];
        s += v[j];
        s2 += v[j] * v[j];
    }
#pragma unroll
    for (int o = 32; o; o >>= 1) {
        s  += __shfl_xor(s, o);
        s2 += __shfl_xor(s2, o);
    }
    const float mu = s * (1.f / 384.f);
    const float var = s2 * (1.f / 384.f) - mu * mu;
    const float rs = 1.f / sqrtf(var + 1e-5f);
#pragma unroll
    for (int j = 0; j < 6; j++) {
        const int c = lane + j * 64;
        const float r = (v[j] - mu) * rs * g[c] + bt[c];
        if (BF16OUT) ((unsigned short*)outp)[(size_t)row * 384 + c] = f2bf(r);
        else         ((float*)outp)[(size_t)row * 384 + c] = r;
    }
}

// ---------------------------------------------------------------------------
// Tiny GEMM (cls path, M<=16), fp32
// ---------------------------------------------------------------------------
__global__ void gemm_small(const float* __restrict__ A, const float* __restrict__ B,
                           const float* __restrict__ bias, float* __restrict__ C,
                           int M, int N, int K, int ldc) {
    const int e = blockIdx.x * 256 + threadIdx.x;
    if (e >= M * N) return;
    const int m = e / N, n = e % N;
    float acc = bias ? bias[n] : 0.f;
    const float* a = A + (size_t)m * K;
    for (int k = 0; k < K; k++) acc += a[k] * B[(size_t)k * N + n];
    C[(size_t)m * ldc + n] = acc;
}

// ---------------------------------------------------------------------------
// cls attention (verified)
// ---------------------------------------------------------------------------
__global__ void attn_cls_kernel(const float* __restrict__ qv, const float* __restrict__ kcls,
                                float* __restrict__ aflat, float* __restrict__ cls_pre) {
    const int b = blockIdx.x;
    const int t = threadIdx.x;  // 64
    __shared__ float kb[384];
    __shared__ float pl[60];
#pragma unroll
    for (int j = 0; j < 6; j++) kb[t + j * 64] = kcls[b * 384 + t + j * 64];
    __syncthreads();
    if (t < 60) {
        const int n = t / 6, h = t % 6;
        float acc = 0.f;
        for (int d = 0; d < 64; d++) acc += qv[n * 768 + h * 64 + d] * kb[h * 64 + d];
        pl[t] = acc * SCL;
    }
    __syncthreads();
    if (t < 6) {
        float m = -1e30f;
        for (int n = 0; n < 10; n++) m = fmaxf(m, pl[n * 6 + t]);
        float p[10], sum = 0.f;
        for (int n = 0; n < 10; n++) { p[n] = expf(pl[n * 6 + t] - m); sum += p[n]; }
        const float inv = 1.f / sum;
        for (int n = 0; n < 10; n++) {
            const float pr = p[n] * inv;
            pl[n * 6 + t] = pr;
            aflat[b * 60 + n * 6 + t] = pr;   // reference flat (n,h) order
        }
    }
    __syncthreads();
#pragma unroll
    for (int j = 0; j < 6; j++) {
        const int c = t + j * 64;
        const int h = c >> 6;
        float acc = 0.f;
        for (int n = 0; n < 10; n++) acc += pl[n * 6 + h] * qv[n * 768 + 384 + c];
        cls_pre[b * 384 + c] = acc;
    }
}

// ---------------------------------------------------------------------------
// Weight transpose-cast: Wt[n][k] = bf16(W[k][n]). grid (N/64, K/64), 256 thr.
// ---------------------------------------------------------------------------
__global__ void wcast_t(const float* __restrict__ W, unsigned short* __restrict__ Wt,
                        int K, int N) {
    const int n0 = blockIdx.x * 64, k0 = blockIdx.y * 64;
    __shared__ unsigned short sT[64][72];
    const int t = threadIdx.x;
    for (int e = t; e < 4096; e += 256) {
        const int k = e >> 6, n = e & 63;
        sT[n][k] = f2bf(W[(size_t)(k0 + k) * N + n0 + n]);
    }
    __syncthreads();
    for (int e = t; e < 512; e += 256) {
        const int n = e >> 3, ch = e & 7;
        *(uint4*)&Wt[(size_t)(n0 + n) * K + k0 + ch * 8] = *(uint4*)&sT[n][ch * 8];
    }
}

// ---------------------------------------------------------------------------
// bf16 MFMA GEMM: C = epilogue(A @ Bt^T). A [M][K] bf16 row-major,
// Bt [N][K] bf16 (transposed weight). BM=64, BN=128, BK=64, 256 threads.
// Wave w -> (wr=w>>1, wc=w&1): 32x64 sub-tile, acc[2][4] f32x4.
// Fragment pattern identical to rz/yz (verified end-to-end):
//   out row = tile(a-op) + lk*4+i, out col = tile(b-op) + lr.
// EPI: 0 bf16-out plain; 1 fp32 +bias +res REMAP (row->row+row/196+1);
//      2 bf16 +bias +GELU; 3 fp32 +bias +res.
// ---------------------------------------------------------------------------
template <int EPI>
__launch_bounds__(256)
__global__ void gemm_mfma(const unsigned short* __restrict__ A,
                          const unsigned short* __restrict__ Bt,
                          const float* __restrict__ bias, const float* __restrict__ res,
                          void* __restrict__ Cout, int M, int N, int K) {
    const int m0 = blockIdx.y * 64, n0 = blockIdx.x * 128;
    const int t = threadIdx.x;
    const int w = t >> 6, l = t & 63;
    const int lr = l & 15, lk = l >> 4;
    const int wr = w >> 1, wc = w & 1;

    __shared__ unsigned short sA[64][72];
    __shared__ unsigned short sB[128][72];

    f32x4 acc[2][4];
#pragma unroll
    for (int mi = 0; mi < 2; mi++)
#pragma unroll
        for (int nj = 0; nj < 4; nj++) acc[mi][nj] = (f32x4){0.f, 0.f, 0.f, 0.f};

    for (int k0 = 0; k0 < K; k0 += 64) {
        for (int e = t; e < 512; e += 256) {
            const int r = e >> 3, ch = e & 7;
            uint4 v = make_uint4(0, 0, 0, 0);
            const int row = m0 + r;
            if (row < M) v = *(const uint4*)(A + (size_t)row * K + k0 + ch * 8);
            *(uint4*)&sA[r][ch * 8] = v;
        }
        for (int e = t; e < 1024; e += 256) {
            const int r = e >> 3, ch = e & 7;
            *(uint4*)&sB[r][ch * 8] = *(const uint4*)(Bt + (size_t)(n0 + r) * K + k0 + ch * 8);
        }
        __syncthreads();
#pragma unroll
        for (int kc = 0; kc < 2; kc++) {
            bf16x8 af[2], bfr[4];
#pragma unroll
            for (int mi = 0; mi < 2; mi++)
                af[mi] = *(const bf16x8*)&sA[wr * 32 + mi * 16 + lr][kc * 32 + lk * 8];
#pragma unroll
            for (int nj = 0; nj < 4; nj++)
                bfr[nj] = *(const bf16x8*)&sB[wc * 64 + nj * 16 + lr][kc * 32 + lk * 8];
#pragma unroll
            for (int mi = 0; mi < 2; mi++)
#pragma unroll
                for (int nj = 0; nj < 4; nj++)
                    acc[mi][nj] = MFMA16(af[mi], bfr[nj], acc[mi][nj]);
        }
        __syncthreads();
    }

#pragma unroll
    for (int mi = 0; mi < 2; mi++)
#pragma unroll
        for (int nj = 0; nj < 4; nj++) {
            const int col = n0 + wc * 64 + nj * 16 + lr;
#pragma unroll
            for (int i = 0; i < 4; i++) {
                const int row = m0 + wr * 32 + mi * 16 + lk * 4 + i;
                if (row >= M) continue;
                float v = acc[mi][nj][i];
                if (EPI == 0) {
                    ((unsigned short*)Cout)[(size_t)row * N + col] = f2bf(v);
                } else if (EPI == 1) {
                    const int crow = row + row / 196 + 1;
                    v += bias[col] + res[(size_t)crow * N + col];
                    ((float*)Cout)[(size_t)crow * N + col] = v;
                } else if (EPI == 2) {
                    ((unsigned short*)Cout)[(size_t)row * N + col] = f2bf(gelu_exact(v + bias[col]));
                } else {
                    v += bias[col] + res[(size_t)row * N + col];
                    ((float*)Cout)[(size_t)row * N + col] = v;
                }
            }
        }
}

// ===========================================================================
// MFMA chain, stage A:  Zt[b,h,c][d][m] = sum_k relu(SCL*k2_c[m]·q2_b[k]) * vr_b[k,d]
// (verified round 3)
// ===========================================================================
__global__ __launch_bounds__(256, 1)
void rz_kernel(const unsigned short* __restrict__ Q2b, const unsigned short* __restrict__ K2b,
               const unsigned short* __restrict__ VRb, unsigned short* __restrict__ Zt) {
    const int c = blockIdx.x, h = blockIdx.y, b = blockIdx.z;
    const int t = threadIdx.x;
    const int w = t >> 6, l = t & 63;
    const int lr = l & 15;
    const int lk = l >> 4;

    __shared__ unsigned short sm[78208];
    unsigned short* sQ2 = sm;                     // [208][72]
    unsigned short* sVT = sm;                     // [64][232]  alias, phase 2+
    unsigned short* sK2 = sm + 14976;             // [208][72]
    unsigned short* sR  = sm + 29952;             // [208][232]

    const unsigned short* q2src = Q2b + ((size_t)(b * 196)) * 384 + h * 64;
    const unsigned short* k2src = K2b + ((size_t)(c * 196)) * 384 + h * 64;
    for (int e = t; e < 208 * 8; e += 256) {
        const int r = e >> 3, ch = e & 7;
        uint4 v = make_uint4(0, 0, 0, 0);
        if (r < 196) v = *(const uint4*)(q2src + (size_t)r * 384 + ch * 8);
        *(uint4*)&sQ2[r * 72 + ch * 8] = v;
    }
    for (int e = t; e < 208 * 8; e += 256) {
        const int r = e >> 3, ch = e & 7;
        uint4 v = make_uint4(0, 0, 0, 0);
        if (r < 196) v = *(const uint4*)(k2src + (size_t)r * 384 + ch * 8);
        *(uint4*)&sK2[r * 72 + ch * 8] = v;
    }
    for (int e = t; e < 208 * 16; e += 256) sR[(e >> 4) * 232 + 208 + (e & 15)] = 0;
    __syncthreads();

    for (int tt = w; tt < 169; tt += 4) {
        const int mt = tt / 13, kt = tt % 13;
        f32x4 acc = {0.f, 0.f, 0.f, 0.f};
        bf16x8 a0 = *(const bf16x8*)&sK2[(mt * 16 + lr) * 72 + lk * 8];
        bf16x8 b0 = *(const bf16x8*)&sQ2[(kt * 16 + lr) * 72 + lk * 8];
        acc = MFMA16(a0, b0, acc);
        bf16x8 a1 = *(const bf16x8*)&sK2[(mt * 16 + lr) * 72 + 32 + lk * 8];
        bf16x8 b1 = *(const bf16x8*)&sQ2[(kt * 16 + lr) * 72 + 32 + lk * 8];
        acc = MFMA16(a1, b1, acc);
        const int rrow = mt * 16 + lk * 4, rcol = kt * 16 + lr;
#pragma unroll
        for (int i = 0; i < 4; i++)
            sR[(rrow + i) * 232 + rcol] = f2bf(fmaxf(0.f, SCL * acc[i]));
    }
    __syncthreads();

    const unsigned short* vrsrc = VRb + ((size_t)(b * 196)) * 384 + h * 64;
    for (int e = t; e < 196 * 8; e += 256) {
        const int kk = e >> 3, ch = e & 7;
        uint4 v = *(const uint4*)(vrsrc + (size_t)kk * 384 + ch * 8);
        unsigned short vs[8]; *(uint4*)vs = v;
#pragma unroll
        for (int j = 0; j < 8; j++) sVT[(ch * 8 + j) * 232 + kk] = vs[j];
    }
    for (int e = t; e < 64 * 36; e += 256) sVT[(e / 36) * 232 + 196 + (e % 36)] = 0;
    __syncthreads();

    unsigned short* zdst = Zt + ((((size_t)(b * 6 + h)) * 10 + c) * 64) * 208;
    for (int tt = w; tt < 52; tt += 4) {
        const int mt = tt >> 2, dt = tt & 3;
        f32x4 acc = {0.f, 0.f, 0.f, 0.f};
#pragma unroll
        for (int kc = 0; kc < 7; kc++) {
            bf16x8 a = *(const bf16x8*)&sR[(mt * 16 + lr) * 232 + kc * 32 + lk * 8];
            bf16x8 bb = *(const bf16x8*)&sVT[(dt * 16 + lr) * 232 + kc * 32 + lk * 8];
            acc = MFMA16(a, bb, acc);
        }
        unsigned short p[4];
#pragma unroll
        for (int i = 0; i < 4; i++) p[i] = f2bf(acc[i]);
        *(uint2*)&zdst[(size_t)(dt * 16 + lr) * 208 + mt * 16 + lk * 4] = *(uint2*)p;
    }
}

// ===========================================================================
// MFMA chain, stage B (verified round 3; now writes bf16 rect).
// ===========================================================================
__global__ __launch_bounds__(256, 1)
void yz_kernel(const unsigned short* __restrict__ QHb, const unsigned short* __restrict__ KHb,
               const unsigned short* __restrict__ Zt, const float* __restrict__ aflat,
               unsigned short* __restrict__ rect) {
    const int ns = blockIdx.x, h = blockIdx.y, b = blockIdx.z;
    const int n0 = ns * 98;
    const int t = threadIdx.x;
    const int w = t >> 6, l = t & 63;
    const int lr = l & 15, lk = l >> 4;

    __shared__ unsigned short sQH[112 * 72];
    __shared__ unsigned short sKH[208 * 72];
    __shared__ unsigned short sZT[64 * 232];
    __shared__ unsigned short sL[112 * 232];

    for (int e = t; e < 112 * 8; e += 256) {
        const int r = e >> 3, ch = e & 7;
        uint4 v = make_uint4(0, 0, 0, 0);
        if (r < 98) v = *(const uint4*)(QHb + ((size_t)(b * 196 + n0 + r)) * 384 + h * 64 + ch * 8);
        *(uint4*)&sQH[r * 72 + ch * 8] = v;
    }
    for (int e = t; e < 112 * 16; e += 256) sL[(e >> 4) * 232 + 208 + (e & 15)] = 0;
    for (int e = t; e < 64 * 24; e += 256) sZT[(e / 24) * 232 + 208 + (e % 24)] = 0;

    f32x4 y[7];
#pragma unroll
    for (int i = 0; i < 7; i++) y[i] = (f32x4){0.f, 0.f, 0.f, 0.f};

    for (int c = 0; c < 10; c++) {
        __syncthreads();
        for (int e = t; e < 208 * 8; e += 256) {
            const int r = e >> 3, ch = e & 7;
            uint4 v = make_uint4(0, 0, 0, 0);
            if (r < 196) v = *(const uint4*)(KHb + ((size_t)(c * 196 + r)) * 384 + h * 64 + ch * 8);
            *(uint4*)&sKH[r * 72 + ch * 8] = v;
        }
        const unsigned short* zsrc = Zt + ((((size_t)(b * 6 + h)) * 10 + c) * 64) * 208;
        for (int e = t; e < 64 * 26; e += 256) {
            const int d = e / 26, mc = e % 26;
            uint4 v = *(const uint4*)(zsrc + (size_t)d * 208 + mc * 8);
            *(uint4*)&sZT[d * 232 + mc * 8] = v;
        }
        const float wc = aflat[b * 60 + h * 10 + c];
        __syncthreads();
        for (int tt = w; tt < 91; tt += 4) {
            const int nt = tt / 13, mt = tt % 13;
            f32x4 acc = {0.f, 0.f, 0.f, 0.f};
            bf16x8 a0 = *(const bf16x8*)&sQH[(nt * 16 + lr) * 72 + lk * 8];
            bf16x8 b0 = *(const bf16x8*)&sKH[(mt * 16 + lr) * 72 + lk * 8];
            acc = MFMA16(a0, b0, acc);
            bf16x8 a1 = *(const bf16x8*)&sQH[(nt * 16 + lr) * 72 + 32 + lk * 8];
            bf16x8 b1 = *(const bf16x8*)&sKH[(mt * 16 + lr) * 72 + 32 + lk * 8];
            acc = MFMA16(a1, b1, acc);
            const int lrow = nt * 16 + lk * 4, lcol = mt * 16 + lr;
#pragma unroll
            for (int i = 0; i < 4; i++)
                sL[(lrow + i) * 232 + lcol] = f2bf(wc * fmaxf(0.f, -SCL * acc[i]));
        }
        __syncthreads();
#pragma unroll
        for (int nt = 0; nt < 7; nt++) {
            f32x4 acc = y[nt];
#pragma unroll
            for (int mc = 0; mc < 7; mc++) {
                bf16x8 a  = *(const bf16x8*)&sL[(nt * 16 + lr) * 232 + mc * 32 + lk * 8];
                bf16x8 bb = *(const bf16x8*)&sZT[(w * 16 + lr) * 232 + mc * 32 + lk * 8];
                acc = MFMA16(a, bb, acc);
            }
            y[nt] = acc;
        }
    }

#pragma unroll
    for (int nt = 0; nt < 7; nt++) {
#pragma unroll
        for (int i = 0; i < 4; i++) {
            const int n = nt * 16 + lk * 4 + i;
            if (n < 98)
                rect[(((size_t)(b * 6 + h)) * 196 + n0 + n) * 64 + w * 16 + lr] = f2bf(y[nt][i]);
        }
    }
}

// ---------------------------------------------------------------------------
// Copy anchors verbatim.
// ---------------------------------------------------------------------------
__global__ void copy_anchors(const float* __restrict__ x, float* __restrict__ out) {
    const int e = blockIdx.x * 256 + threadIdx.x;
    if (e < 189120) {
        const int base = 16 * 197 * 384 / 4;
        ((float4*)out)[base + e] = ((const float4*)x)[base + e];
    }
}

// ---------------------------------------------------------------------------
// kernel_launch. Workspace in f32 units, total 12,655,296 f = 50.6 MB.
// hdn/G alias the Zt region (dead after yz).
// ---------------------------------------------------------------------------
extern "C" void kernel_launch(void* const* d_in, const int* in_sizes, int n_in,
                              void* d_out, int out_size, void* d_ws, size_t ws_size,
                              hipStream_t stream) {
    (void)in_sizes; (void)n_in; (void)out_size; (void)ws_size;
    const float* x       = (const float*)d_in[0];
    const float* Wqv     = (const float*)d_in[1];
    const float* Wk      = (const float*)d_in[2];
    const float* Wq_proj = (const float*)d_in[3];
    const float* bq_proj = (const float*)d_in[4];
    const float* Wqk     = (const float*)d_in[5];
    const float* Wqk2    = (const float*)d_in[6];
    const float* Wv      = (const float*)d_in[7];
    const float* Wr_proj = (const float*)d_in[8];
    const float* br_proj = (const float*)d_in[9];
    const float* g1      = (const float*)d_in[10];
    const float* b1      = (const float*)d_in[11];
    const float* g2      = (const float*)d_in[12];
    const float* b2      = (const float*)d_in[13];
    const float* g3      = (const float*)d_in[14];
    const float* b3      = (const float*)d_in[15];
    const float* W1      = (const float*)d_in[16];
    const float* bm1     = (const float*)d_in[17];
    const float* W2      = (const float*)d_in[18];
    const float* bm2     = (const float*)d_in[19];

    float* ws = (float*)d_ws;
    float* n1      = ws;                                     //      9,984
    float* qv      = ws + 9984;                              //      7,680
    float* kcls    = ws + 17664;                             //      6,144
    float* aflat   = ws + 23808;                             //        960
    float* cls_pre = ws + 24768;                             //      6,144
    unsigned short* n2x_bf  = (unsigned short*)(ws + 30912);   // 3136x384 bf16
    unsigned short* n2a_bf  = (unsigned short*)(ws + 633024);  // 1960x384 bf16
    unsigned short* QHb     = (unsigned short*)(ws + 1009344);
    unsigned short* Q2b     = (unsigned short*)(ws + 1611456);
    unsigned short* VRb     = (unsigned short*)(ws + 2213568);
    unsigned short* KHb     = (unsigned short*)(ws + 2815680);
    unsigned short* K2b     = (unsigned short*)(ws + 3192000);
    unsigned short* rect_bf = (unsigned short*)(ws + 3568320); // 3136x384 bf16
    float* xx               = ws + 4170432;                    // 16x197x384 f32
    unsigned short* Wqk_t   = (unsigned short*)(ws + 5380800);
    unsigned short* Wqk2_t  = (unsigned short*)(ws + 5454528);
    unsigned short* Wv_t    = (unsigned short*)(ws + 5528256);
    unsigned short* Wr_t    = (unsigned short*)(ws + 5601984);
    unsigned short* W1_t    = (unsigned short*)(ws + 5675712); // 1536x384 (as [N][K])
    unsigned short* W2_t    = (unsigned short*)(ws + 5970624); // 384x1536
    unsigned short* Zt      = (unsigned short*)(ws + 6265536); // 96*10*64*208 bf16
    unsigned short* hdn_bf  = (unsigned short*)(ws + 6265536); // alias Zt (dead after yz)
    unsigned short* G_bf    = (unsigned short*)(ws + 6870720); // alias Zt region
    float* outf = (float*)d_out;

    // 0. weight transpose-casts (independent)
    wcast_t<<<dim3(6, 6),  256, 0, stream>>>(Wqk,     Wqk_t,  384, 384);
    wcast_t<<<dim3(6, 6),  256, 0, stream>>>(Wqk2,    Wqk2_t, 384, 384);
    wcast_t<<<dim3(6, 6),  256, 0, stream>>>(Wv,      Wv_t,   384, 384);
    wcast_t<<<dim3(6, 6),  256, 0, stream>>>(Wr_proj, Wr_t,   384, 384);
    wcast_t<<<dim3(24, 6), 256, 0, stream>>>(W1,      W1_t,   384, 1536);
    wcast_t<<<dim3(6, 24), 256, 0, stream>>>(W2,      W2_t,   1536, 384);
    // 1. LN cls tokens (fp32 out)
    ln_kernel<0><<<26, 64, 0, stream>>>(x, n1, g1, b1, 0);
    // 2. qv / kcls (fp32 small)
    gemm_small<<<30, 256, 0, stream>>>(n1 + 16 * 384, Wqv, nullptr, qv, 10, 768, 384, 768);
    gemm_small<<<24, 256, 0, stream>>>(n1, Wk, nullptr, kcls, 16, 384, 384, 384);
    // 3. cls attention
    attn_cls_kernel<<<16, 64, 0, stream>>>(qv, kcls, aflat, cls_pre);
    // 4. LN image tokens (bf16 out)
    ln_kernel<1><<<3136, 64, 0, stream>>>(x, n2x_bf, g2, b2, 1);
    ln_kernel<1><<<1960, 64, 0, stream>>>(x, n2a_bf, g2, b2, 2);
    // 5. head projections (bf16 MFMA, bf16 out)
    gemm_mfma<0><<<dim3(3, 49), 256, 0, stream>>>(n2x_bf, Wqk_t,  nullptr, nullptr, QHb, 3136, 384, 384);
    gemm_mfma<0><<<dim3(3, 49), 256, 0, stream>>>(n2x_bf, Wqk2_t, nullptr, nullptr, Q2b, 3136, 384, 384);
    gemm_mfma<0><<<dim3(3, 49), 256, 0, stream>>>(n2x_bf, Wv_t,   nullptr, nullptr, VRb, 3136, 384, 384);
    gemm_mfma<0><<<dim3(3, 31), 256, 0, stream>>>(n2a_bf, Wqk_t,  nullptr, nullptr, KHb, 1960, 384, 384);
    gemm_mfma<0><<<dim3(3, 31), 256, 0, stream>>>(n2a_bf, Wqk2_t, nullptr, nullptr, K2b, 1960, 384, 384);
    // 6. chain stage A
    rz_kernel<<<dim3(10, 6, 16), 256, 0, stream>>>(Q2b, K2b, VRb, Zt);
    // 7. chain stage B -> rect bf16 (reshape layout)
    yz_kernel<<<dim3(2, 6, 16), 256, 0, stream>>>(QHb, KHb, Zt, aflat, rect_bf);
    // 8. cls_out -> xx token 0
    gemm_small<<<24, 256, 0, stream>>>(cls_pre, Wq_proj, bq_proj, xx, 16, 384, 384, 197 * 384);
    // 9. xx[:,1:] = rect @ Wr_proj + br + x_im  (remapped rows)
    gemm_mfma<1><<<dim3(3, 49), 256, 0, stream>>>(rect_bf, Wr_t, br_proj, x, xx, 3136, 384, 384);
    // 10. LN3 (bf16 out into hdn)
    ln_kernel<1><<<3152, 64, 0, stream>>>(xx, hdn_bf, g3, b3, 3);
    // 11. MLP up + GELU -> bf16 G
    gemm_mfma<2><<<dim3(12, 50), 256, 0, stream>>>(hdn_bf, W1_t, bm1, nullptr, G_bf, 3152, 1536, 384);
    // 12. MLP down + bias + residual -> out rows 0..3151
    gemm_mfma<3><<<dim3(3, 50), 256, 0, stream>>>(G_bf, W2_t, bm2, xx, outf, 3152, 384, 1536);
    // 13. anchors pass-through
    copy_anchors<<<739, 256, 0, stream>>>(x, outf);
}

// Round 6
// 574.054 us; speedup vs baseline: 3.7773x; 1.3290x over previous
//
#include <hip/hip_runtime.h>
#include <hip/hip_bf16.h>
#include <math.h>

#define SCL 0.125f

typedef float f32x4 __attribute__((ext_vector_type(4)));
typedef short bf16x8 __attribute__((ext_vector_type(8)));   // 8 bf16 in 4 VGPRs
#define MFMA16(a, b, c) __builtin_amdgcn_mfma_f32_16x16x32_bf16((a), (b), (c), 0, 0, 0)

// f32 -> bf16 round-to-nearest-even
__device__ __forceinline__ unsigned short f2bf(float f) {
    unsigned int u = __builtin_bit_cast(unsigned int, f);
    u = (u + 0x7FFFu + ((u >> 16) & 1u)) >> 16;
    return (unsigned short)u;
}

__device__ __forceinline__ float gelu_exact(float v) {
    return 0.5f * v * (1.f + erff(v * 0.70710678118654752f));
}

// ---------------------------------------------------------------------------
// LayerNorm over last dim (384). One wave per row. BF16OUT picks dst type.
// ---------------------------------------------------------------------------
template <int BF16OUT>
__global__ void ln_kernel(const float* __restrict__ x, void* __restrict__ outp,
                          const float* __restrict__ g, const float* __restrict__ bt,
                          int mode) {
    const int row = blockIdx.x;
    const int lane = threadIdx.x;           // 64 threads
    const float* src;
    if (mode == 0)      src = x + (size_t)row * (197 * 384);
    else if (mode == 1) { int b = row / 196, n = row % 196; src = x + (size_t)(b * 197 + 1 + n) * 384; }
    else if (mode == 2) { int b = row / 196, n = row % 196; src = x + (size_t)((16 + b) * 197 + 1 + n) * 384; }
    else                src = x + (size_t)row * 384;

    float v[6];
    float s = 0.f, s2 = 0.f;
#pragma unroll
    for (int j = 0; j < 6; j++) {
        v[j] = src[lane + j * 64];
        s += v[j];
        s2 += v[j] * v[j];
    }
#pragma unroll
    for (int o = 32; o; o >>= 1) {
        s  += __shfl_xor(s, o);
        s2 += __shfl_xor(s2, o);
    }
    const float mu = s * (1.f / 384.f);
    const float var = s2 * (1.f / 384.f) - mu * mu;
    const float rs = 1.f / sqrtf(var + 1e-5f);
#pragma unroll
    for (int j = 0; j < 6; j++) {
        const int c = lane + j * 64;
        const float r = (v[j] - mu) * rs * g[c] + bt[c];
        if (BF16OUT) ((unsigned short*)outp)[(size_t)row * 384 + c] = f2bf(r);
        else         ((float*)outp)[(size_t)row * 384 + c] = r;
    }
}

// ---------------------------------------------------------------------------
// cls-path GEMM, latency-optimized (replaces gemm_small, which was 140 µs
// at VALUBusy 0.14%: 1-thread-per-element, un-unrolled K loop = serial L2
// latency chain). A [M][384] staged in LDS; 256 thr = 64 coalesced cols x
// 4 k-slices; M independent accumulators -> ILP; LDS reduce over slices.
// ---------------------------------------------------------------------------
template <int M>
__global__ void gemm_cls(const float* __restrict__ A, const float* __restrict__ B,
                         const float* __restrict__ bias, float* __restrict__ C,
                         int N, int ldc) {
    __shared__ float sA[M * 384];
    __shared__ float red[4][M][64];
    const int t = threadIdx.x;
    const int tc = t & 63, ks = t >> 6;
    const int n = blockIdx.x * 64 + tc;
    for (int e = t; e < M * 384; e += 256) sA[e] = A[e];
    __syncthreads();
    float acc[M];
#pragma unroll
    for (int m = 0; m < M; m++) acc[m] = 0.f;
    const int k0 = ks * 96;
#pragma unroll 4
    for (int k = k0; k < k0 + 96; k++) {
        const float bv = B[(size_t)k * N + n];
#pragma unroll
        for (int m = 0; m < M; m++) acc[m] += sA[m * 384 + k] * bv;
    }
#pragma unroll
    for (int m = 0; m < M; m++) red[ks][m][tc] = acc[m];
    __syncthreads();
    if (ks == 0) {
#pragma unroll
        for (int m = 0; m < M; m++) {
            float s = red[0][m][tc] + red[1][m][tc] + red[2][m][tc] + red[3][m][tc];
            if (bias) s += bias[n];
            C[(size_t)m * ldc + n] = s;
        }
    }
}

// ---------------------------------------------------------------------------
// cls attention (verified)
// ---------------------------------------------------------------------------
__global__ void attn_cls_kernel(const float* __restrict__ qv, const float* __restrict__ kcls,
                                float* __restrict__ aflat, float* __restrict__ cls_pre) {
    const int b = blockIdx.x;
    const int t = threadIdx.x;  // 64
    __shared__ float kb[384];
    __shared__ float pl[60];
#pragma unroll
    for (int j = 0; j < 6; j++) kb[t + j * 64] = kcls[b * 384 + t + j * 64];
    __syncthreads();
    if (t < 60) {
        const int n = t / 6, h = t % 6;
        float acc = 0.f;
        for (int d = 0; d < 64; d++) acc += qv[n * 768 + h * 64 + d] * kb[h * 64 + d];
        pl[t] = acc * SCL;
    }
    __syncthreads();
    if (t < 6) {
        float m = -1e30f;
        for (int n = 0; n < 10; n++) m = fmaxf(m, pl[n * 6 + t]);
        float p[10], sum = 0.f;
        for (int n = 0; n < 10; n++) { p[n] = expf(pl[n * 6 + t] - m); sum += p[n]; }
        const float inv = 1.f / sum;
        for (int n = 0; n < 10; n++) {
            const float pr = p[n] * inv;
            pl[n * 6 + t] = pr;
            aflat[b * 60 + n * 6 + t] = pr;   // reference flat (n,h) order
        }
    }
    __syncthreads();
#pragma unroll
    for (int j = 0; j < 6; j++) {
        const int c = t + j * 64;
        const int h = c >> 6;
        float acc = 0.f;
        for (int n = 0; n < 10; n++) acc += pl[n * 6 + h] * qv[n * 768 + 384 + c];
        cls_pre[b * 384 + c] = acc;
    }
}

// ---------------------------------------------------------------------------
// Weight transpose-cast: Wt[n][k] = bf16(W[k][n]). grid (N/64, K/64), 256 thr.
// ---------------------------------------------------------------------------
__global__ void wcast_t(const float* __restrict__ W, unsigned short* __restrict__ Wt,
                        int K, int N) {
    const int n0 = blockIdx.x * 64, k0 = blockIdx.y * 64;
    __shared__ unsigned short sT[64][72];
    const int t = threadIdx.x;
    for (int e = t; e < 4096; e += 256) {
        const int k = e >> 6, n = e & 63;
        sT[n][k] = f2bf(W[(size_t)(k0 + k) * N + n0 + n]);
    }
    __syncthreads();
    for (int e = t; e < 512; e += 256) {
        const int n = e >> 3, ch = e & 7;
        *(uint4*)&Wt[(size_t)(n0 + n) * K + k0 + ch * 8] = *(uint4*)&sT[n][ch * 8];
    }
}

// ---------------------------------------------------------------------------
// bf16 MFMA GEMM: C = epilogue(A @ Bt^T). A [M][K] bf16 row-major,
// Bt [N][K] bf16 (transposed weight). BM=64, BN=128, BK=64, 256 threads.
// EPI: 0 bf16-out plain; 1 fp32 +bias +res REMAP (row->row+row/196+1);
//      2 bf16 +bias +GELU; 3 fp32 +bias +res.
// ---------------------------------------------------------------------------
template <int EPI>
__launch_bounds__(256)
__global__ void gemm_mfma(const unsigned short* __restrict__ A,
                          const unsigned short* __restrict__ Bt,
                          const float* __restrict__ bias, const float* __restrict__ res,
                          void* __restrict__ Cout, int M, int N, int K) {
    const int m0 = blockIdx.y * 64, n0 = blockIdx.x * 128;
    const int t = threadIdx.x;
    const int w = t >> 6, l = t & 63;
    const int lr = l & 15, lk = l >> 4;
    const int wr = w >> 1, wc = w & 1;

    __shared__ unsigned short sA[64][72];
    __shared__ unsigned short sB[128][72];

    f32x4 acc[2][4];
#pragma unroll
    for (int mi = 0; mi < 2; mi++)
#pragma unroll
        for (int nj = 0; nj < 4; nj++) acc[mi][nj] = (f32x4){0.f, 0.f, 0.f, 0.f};

    for (int k0 = 0; k0 < K; k0 += 64) {
        for (int e = t; e < 512; e += 256) {
            const int r = e >> 3, ch = e & 7;
            uint4 v = make_uint4(0, 0, 0, 0);
            const int row = m0 + r;
            if (row < M) v = *(const uint4*)(A + (size_t)row * K + k0 + ch * 8);
            *(uint4*)&sA[r][ch * 8] = v;
        }
        for (int e = t; e < 1024; e += 256) {
            const int r = e >> 3, ch = e & 7;
            *(uint4*)&sB[r][ch * 8] = *(const uint4*)(Bt + (size_t)(n0 + r) * K + k0 + ch * 8);
        }
        __syncthreads();
#pragma unroll
        for (int kc = 0; kc < 2; kc++) {
            bf16x8 af[2], bfr[4];
#pragma unroll
            for (int mi = 0; mi < 2; mi++)
                af[mi] = *(const bf16x8*)&sA[wr * 32 + mi * 16 + lr][kc * 32 + lk * 8];
#pragma unroll
            for (int nj = 0; nj < 4; nj++)
                bfr[nj] = *(const bf16x8*)&sB[wc * 64 + nj * 16 + lr][kc * 32 + lk * 8];
#pragma unroll
            for (int mi = 0; mi < 2; mi++)
#pragma unroll
                for (int nj = 0; nj < 4; nj++)
                    acc[mi][nj] = MFMA16(af[mi], bfr[nj], acc[mi][nj]);
        }
        __syncthreads();
    }

#pragma unroll
    for (int mi = 0; mi < 2; mi++)
#pragma unroll
        for (int nj = 0; nj < 4; nj++) {
            const int col = n0 + wc * 64 + nj * 16 + lr;
#pragma unroll
            for (int i = 0; i < 4; i++) {
                const int row = m0 + wr * 32 + mi * 16 + lk * 4 + i;
                if (row >= M) continue;
                float v = acc[mi][nj][i];
                if (EPI == 0) {
                    ((unsigned short*)Cout)[(size_t)row * N + col] = f2bf(v);
                } else if (EPI == 1) {
                    const int crow = row + row / 196 + 1;
                    v += bias[col] + res[(size_t)crow * N + col];
                    ((float*)Cout)[(size_t)crow * N + col] = v;
                } else if (EPI == 2) {
                    ((unsigned short*)Cout)[(size_t)row * N + col] = f2bf(gelu_exact(v + bias[col]));
                } else {
                    v += bias[col] + res[(size_t)row * N + col];
                    ((float*)Cout)[(size_t)row * N + col] = v;
                }
            }
        }
}

// ===========================================================================
// MFMA chain, stage A:  Zt[b,h,c][d][m] = sum_k relu(SCL*k2_c[m]·q2_b[k]) * vr_b[k,d]
// (verified round 3)
// ===========================================================================
__global__ __launch_bounds__(256, 1)
void rz_kernel(const unsigned short* __restrict__ Q2b, const unsigned short* __restrict__ K2b,
               const unsigned short* __restrict__ VRb, unsigned short* __restrict__ Zt) {
    const int c = blockIdx.x, h = blockIdx.y, b = blockIdx.z;
    const int t = threadIdx.x;
    const int w = t >> 6, l = t & 63;
    const int lr = l & 15;
    const int lk = l >> 4;

    __shared__ unsigned short sm[78208];
    unsigned short* sQ2 = sm;                     // [208][72]
    unsigned short* sVT = sm;                     // [64][232]  alias, phase 2+
    unsigned short* sK2 = sm + 14976;             // [208][72]
    unsigned short* sR  = sm + 29952;             // [208][232]

    const unsigned short* q2src = Q2b + ((size_t)(b * 196)) * 384 + h * 64;
    const unsigned short* k2src = K2b + ((size_t)(c * 196)) * 384 + h * 64;
    for (int e = t; e < 208 * 8; e += 256) {
        const int r = e >> 3, ch = e & 7;
        uint4 v = make_uint4(0, 0, 0, 0);
        if (r < 196) v = *(const uint4*)(q2src + (size_t)r * 384 + ch * 8);
        *(uint4*)&sQ2[r * 72 + ch * 8] = v;
    }
    for (int e = t; e < 208 * 8; e += 256) {
        const int r = e >> 3, ch = e & 7;
        uint4 v = make_uint4(0, 0, 0, 0);
        if (r < 196) v = *(const uint4*)(k2src + (size_t)r * 384 + ch * 8);
        *(uint4*)&sK2[r * 72 + ch * 8] = v;
    }
    for (int e = t; e < 208 * 16; e += 256) sR[(e >> 4) * 232 + 208 + (e & 15)] = 0;
    __syncthreads();

    for (int tt = w; tt < 169; tt += 4) {
        const int mt = tt / 13, kt = tt % 13;
        f32x4 acc = {0.f, 0.f, 0.f, 0.f};
        bf16x8 a0 = *(const bf16x8*)&sK2[(mt * 16 + lr) * 72 + lk * 8];
        bf16x8 b0 = *(const bf16x8*)&sQ2[(kt * 16 + lr) * 72 + lk * 8];
        acc = MFMA16(a0, b0, acc);
        bf16x8 a1 = *(const bf16x8*)&sK2[(mt * 16 + lr) * 72 + 32 + lk * 8];
        bf16x8 b1 = *(const bf16x8*)&sQ2[(kt * 16 + lr) * 72 + 32 + lk * 8];
        acc = MFMA16(a1, b1, acc);
        const int rrow = mt * 16 + lk * 4, rcol = kt * 16 + lr;
#pragma unroll
        for (int i = 0; i < 4; i++)
            sR[(rrow + i) * 232 + rcol] = f2bf(fmaxf(0.f, SCL * acc[i]));
    }
    __syncthreads();

    const unsigned short* vrsrc = VRb + ((size_t)(b * 196)) * 384 + h * 64;
    for (int e = t; e < 196 * 8; e += 256) {
        const int kk = e >> 3, ch = e & 7;
        uint4 v = *(const uint4*)(vrsrc + (size_t)kk * 384 + ch * 8);
        unsigned short vs[8]; *(uint4*)vs = v;
#pragma unroll
        for (int j = 0; j < 8; j++) sVT[(ch * 8 + j) * 232 + kk] = vs[j];
    }
    for (int e = t; e < 64 * 36; e += 256) sVT[(e / 36) * 232 + 196 + (e % 36)] = 0;
    __syncthreads();

    unsigned short* zdst = Zt + ((((size_t)(b * 6 + h)) * 10 + c) * 64) * 208;
    for (int tt = w; tt < 52; tt += 4) {
        const int mt = tt >> 2, dt = tt & 3;
        f32x4 acc = {0.f, 0.f, 0.f, 0.f};
#pragma unroll
        for (int kc = 0; kc < 7; kc++) {
            bf16x8 a = *(const bf16x8*)&sR[(mt * 16 + lr) * 232 + kc * 32 + lk * 8];
            bf16x8 bb = *(const bf16x8*)&sVT[(dt * 16 + lr) * 232 + kc * 32 + lk * 8];
            acc = MFMA16(a, bb, acc);
        }
        unsigned short p[4];
#pragma unroll
        for (int i = 0; i < 4; i++) p[i] = f2bf(acc[i]);
        *(uint2*)&zdst[(size_t)(dt * 16 + lr) * 208 + mt * 16 + lk * 4] = *(uint2*)p;
    }
}

// ===========================================================================
// MFMA chain, stage B (verified round 3; writes bf16 rect).
// ===========================================================================
__global__ __launch_bounds__(256, 1)
void yz_kernel(const unsigned short* __restrict__ QHb, const unsigned short* __restrict__ KHb,
               const unsigned short* __restrict__ Zt, const float* __restrict__ aflat,
               unsigned short* __restrict__ rect) {
    const int ns = blockIdx.x, h = blockIdx.y, b = blockIdx.z;
    const int n0 = ns * 98;
    const int t = threadIdx.x;
    const int w = t >> 6, l = t & 63;
    const int lr = l & 15, lk = l >> 4;

    __shared__ unsigned short sQH[112 * 72];
    __shared__ unsigned short sKH[208 * 72];
    __shared__ unsigned short sZT[64 * 232];
    __shared__ unsigned short sL[112 * 232];

    for (int e = t; e < 112 * 8; e += 256) {
        const int r = e >> 3, ch = e & 7;
        uint4 v = make_uint4(0, 0, 0, 0);
        if (r < 98) v = *(const uint4*)(QHb + ((size_t)(b * 196 + n0 + r)) * 384 + h * 64 + ch * 8);
        *(uint4*)&sQH[r * 72 + ch * 8] = v;
    }
    for (int e = t; e < 112 * 16; e += 256) sL[(e >> 4) * 232 + 208 + (e & 15)] = 0;
    for (int e = t; e < 64 * 24; e += 256) sZT[(e / 24) * 232 + 208 + (e % 24)] = 0;

    f32x4 y[7];
#pragma unroll
    for (int i = 0; i < 7; i++) y[i] = (f32x4){0.f, 0.f, 0.f, 0.f};

    for (int c = 0; c < 10; c++) {
        __syncthreads();
        for (int e = t; e < 208 * 8; e += 256) {
            const int r = e >> 3, ch = e & 7;
            uint4 v = make_uint4(0, 0, 0, 0);
            if (r < 196) v = *(const uint4*)(KHb + ((size_t)(c * 196 + r)) * 384 + h * 64 + ch * 8);
            *(uint4*)&sKH[r * 72 + ch * 8] = v;
        }
        const unsigned short* zsrc = Zt + ((((size_t)(b * 6 + h)) * 10 + c) * 64) * 208;
        for (int e = t; e < 64 * 26; e += 256) {
            const int d = e / 26, mc = e % 26;
            uint4 v = *(const uint4*)(zsrc + (size_t)d * 208 + mc * 8);
            *(uint4*)&sZT[d * 232 + mc * 8] = v;
        }
        const float wc = aflat[b * 60 + h * 10 + c];
        __syncthreads();
        for (int tt = w; tt < 91; tt += 4) {
            const int nt = tt / 13, mt = tt % 13;
            f32x4 acc = {0.f, 0.f, 0.f, 0.f};
            bf16x8 a0 = *(const bf16x8*)&sQH[(nt * 16 + lr) * 72 + lk * 8];
            bf16x8 b0 = *(const bf16x8*)&sKH[(mt * 16 + lr) * 72 + lk * 8];
            acc = MFMA16(a0, b0, acc);
            bf16x8 a1 = *(const bf16x8*)&sQH[(nt * 16 + lr) * 72 + 32 + lk * 8];
            bf16x8 b1 = *(const bf16x8*)&sKH[(mt * 16 + lr) * 72 + 32 + lk * 8];
            acc = MFMA16(a1, b1, acc);
            const int lrow = nt * 16 + lk * 4, lcol = mt * 16 + lr;
#pragma unroll
            for (int i = 0; i < 4; i++)
                sL[(lrow + i) * 232 + lcol] = f2bf(wc * fmaxf(0.f, -SCL * acc[i]));
        }
        __syncthreads();
#pragma unroll
        for (int nt = 0; nt < 7; nt++) {
            f32x4 acc = y[nt];
#pragma unroll
            for (int mc = 0; mc < 7; mc++) {
                bf16x8 a  = *(const bf16x8*)&sL[(nt * 16 + lr) * 232 + mc * 32 + lk * 8];
                bf16x8 bb = *(const bf16x8*)&sZT[(w * 16 + lr) * 232 + mc * 32 + lk * 8];
                acc = MFMA16(a, bb, acc);
            }
            y[nt] = acc;
        }
    }

#pragma unroll
    for (int nt = 0; nt < 7; nt++) {
#pragma unroll
        for (int i = 0; i < 4; i++) {
            const int n = nt * 16 + lk * 4 + i;
            if (n < 98)
                rect[(((size_t)(b * 6 + h)) * 196 + n0 + n) * 64 + w * 16 + lr] = f2bf(y[nt][i]);
        }
    }
}

// ---------------------------------------------------------------------------
// Copy anchors verbatim.
// ---------------------------------------------------------------------------
__global__ void copy_anchors(const float* __restrict__ x, float* __restrict__ out) {
    const int e = blockIdx.x * 256 + threadIdx.x;
    if (e < 189120) {
        const int base = 16 * 197 * 384 / 4;
        ((float4*)out)[base + e] = ((const float4*)x)[base + e];
    }
}

// ---------------------------------------------------------------------------
// kernel_launch. Workspace in f32 units, total 12,655,296 f = 50.6 MB.
// hdn/G alias the Zt region (dead after yz).
// ---------------------------------------------------------------------------
extern "C" void kernel_launch(void* const* d_in, const int* in_sizes, int n_in,
                              void* d_out, int out_size, void* d_ws, size_t ws_size,
                              hipStream_t stream) {
    (void)in_sizes; (void)n_in; (void)out_size; (void)ws_size;
    const float* x       = (const float*)d_in[0];
    const float* Wqv     = (const float*)d_in[1];
    const float* Wk      = (const float*)d_in[2];
    const float* Wq_proj = (const float*)d_in[3];
    const float* bq_proj = (const float*)d_in[4];
    const float* Wqk     = (const float*)d_in[5];
    const float* Wqk2    = (const float*)d_in[6];
    const float* Wv      = (const float*)d_in[7];
    const float* Wr_proj = (const float*)d_in[8];
    const float* br_proj = (const float*)d_in[9];
    const float* g1      = (const float*)d_in[10];
    const float* b1      = (const float*)d_in[11];
    const float* g2      = (const float*)d_in[12];
    const float* b2      = (const float*)d_in[13];
    const float* g3      = (const float*)d_in[14];
    const float* b3      = (const float*)d_in[15];
    const float* W1      = (const float*)d_in[16];
    const float* bm1     = (const float*)d_in[17];
    const float* W2      = (const float*)d_in[18];
    const float* bm2     = (const float*)d_in[19];

    float* ws = (float*)d_ws;
    float* n1      = ws;                                     //      9,984
    float* qv      = ws + 9984;                              //      7,680
    float* kcls    = ws + 17664;                             //      6,144
    float* aflat   = ws + 23808;                             //        960
    float* cls_pre = ws + 24768;                             //      6,144
    unsigned short* n2x_bf  = (unsigned short*)(ws + 30912);   // 3136x384 bf16
    unsigned short* n2a_bf  = (unsigned short*)(ws + 633024);  // 1960x384 bf16
    unsigned short* QHb     = (unsigned short*)(ws + 1009344);
    unsigned short* Q2b     = (unsigned short*)(ws + 1611456);
    unsigned short* VRb     = (unsigned short*)(ws + 2213568);
    unsigned short* KHb     = (unsigned short*)(ws + 2815680);
    unsigned short* K2b     = (unsigned short*)(ws + 3192000);
    unsigned short* rect_bf = (unsigned short*)(ws + 3568320); // 3136x384 bf16
    float* xx               = ws + 4170432;                    // 16x197x384 f32
    unsigned short* Wqk_t   = (unsigned short*)(ws + 5380800);
    unsigned short* Wqk2_t  = (unsigned short*)(ws + 5454528);
    unsigned short* Wv_t    = (unsigned short*)(ws + 5528256);
    unsigned short* Wr_t    = (unsigned short*)(ws + 5601984);
    unsigned short* W1_t    = (unsigned short*)(ws + 5675712); // 1536x384 (as [N][K])
    unsigned short* W2_t    = (unsigned short*)(ws + 5970624); // 384x1536
    unsigned short* Zt      = (unsigned short*)(ws + 6265536); // 96*10*64*208 bf16
    unsigned short* hdn_bf  = (unsigned short*)(ws + 6265536); // alias Zt (dead after yz)
    unsigned short* G_bf    = (unsigned short*)(ws + 6870720); // alias Zt region
    float* outf = (float*)d_out;

    // 0. weight transpose-casts (independent)
    wcast_t<<<dim3(6, 6),  256, 0, stream>>>(Wqk,     Wqk_t,  384, 384);
    wcast_t<<<dim3(6, 6),  256, 0, stream>>>(Wqk2,    Wqk2_t, 384, 384);
    wcast_t<<<dim3(6, 6),  256, 0, stream>>>(Wv,      Wv_t,   384, 384);
    wcast_t<<<dim3(6, 6),  256, 0, stream>>>(Wr_proj, Wr_t,   384, 384);
    wcast_t<<<dim3(24, 6), 256, 0, stream>>>(W1,      W1_t,   384, 1536);
    wcast_t<<<dim3(6, 24), 256, 0, stream>>>(W2,      W2_t,   1536, 384);
    // 1. LN cls tokens (fp32 out)
    ln_kernel<0><<<26, 64, 0, stream>>>(x, n1, g1, b1, 0);
    // 2. qv / kcls (latency-optimized cls GEMMs)
    gemm_cls<10><<<12, 256, 0, stream>>>(n1 + 16 * 384, Wqv, nullptr, qv, 768, 768);
    gemm_cls<16><<<6, 256, 0, stream>>>(n1, Wk, nullptr, kcls, 384, 384);
    // 3. cls attention
    attn_cls_kernel<<<16, 64, 0, stream>>>(qv, kcls, aflat, cls_pre);
    // 4. LN image tokens (bf16 out)
    ln_kernel<1><<<3136, 64, 0, stream>>>(x, n2x_bf, g2, b2, 1);
    ln_kernel<1><<<1960, 64, 0, stream>>>(x, n2a_bf, g2, b2, 2);
    // 5. head projections (bf16 MFMA, bf16 out)
    gemm_mfma<0><<<dim3(3, 49), 256, 0, stream>>>(n2x_bf, Wqk_t,  nullptr, nullptr, QHb, 3136, 384, 384);
    gemm_mfma<0><<<dim3(3, 49), 256, 0, stream>>>(n2x_bf, Wqk2_t, nullptr, nullptr, Q2b, 3136, 384, 384);
    gemm_mfma<0><<<dim3(3, 49), 256, 0, stream>>>(n2x_bf, Wv_t,   nullptr, nullptr, VRb, 3136, 384, 384);
    gemm_mfma<0><<<dim3(3, 31), 256, 0, stream>>>(n2a_bf, Wqk_t,  nullptr, nullptr, KHb, 1960, 384, 384);
    gemm_mfma<0><<<dim3(3, 31), 256, 0, stream>>>(n2a_bf, Wqk2_t, nullptr, nullptr, K2b, 1960, 384, 384);
    // 6. chain stage A
    rz_kernel<<<dim3(10, 6, 16), 256, 0, stream>>>(Q2b, K2b, VRb, Zt);
    // 7. chain stage B -> rect bf16 (reshape layout)
    yz_kernel<<<dim3(2, 6, 16), 256, 0, stream>>>(QHb, KHb, Zt, aflat, rect_bf);
    // 8. cls_out -> xx token 0
    gemm_cls<16><<<6, 256, 0, stream>>>(cls_pre, Wq_proj, bq_proj, xx, 384, 197 * 384);
    // 9. xx[:,1:] = rect @ Wr_proj + br + x_im  (remapped rows)
    gemm_mfma<1><<<dim3(3, 49), 256, 0, stream>>>(rect_bf, Wr_t, br_proj, x, xx, 3136, 384, 384);
    // 10. LN3 (bf16 out into hdn)
    ln_kernel<1><<<3152, 64, 0, stream>>>(xx, hdn_bf, g3, b3, 3);
    // 11. MLP up + GELU -> bf16 G
    gemm_mfma<2><<<dim3(12, 50), 256, 0, stream>>>(hdn_bf, W1_t, bm1, nullptr, G_bf, 3152, 1536, 384);
    // 12. MLP down + bias + residual -> out rows 0..3151
    gemm_mfma<3><<<dim3(3, 50), 256, 0, stream>>>(G_bf, W2_t, bm2, xx, outf, 3152, 384, 1536);
    // 13. anchors pass-through
    copy_anchors<<<739, 256, 0, stream>>>(x, outf);
}

// Round 8
// 503.426 us; speedup vs baseline: 4.3073x; 1.1403x over previous
//
#include <hip/hip_runtime.h>
#include <hip/hip_bf16.h>
#include <math.h>

#define SCL 0.125f

typedef float f32x4 __attribute__((ext_vector_type(4)));
typedef short bf16x8 __attribute__((ext_vector_type(8)));   // 8 bf16 in 4 VGPRs
#define MFMA16(a, b, c) __builtin_amdgcn_mfma_f32_16x16x32_bf16((a), (b), (c), 0, 0, 0)

// f32 -> bf16 round-to-nearest-even
__device__ __forceinline__ unsigned short f2bf(float f) {
    unsigned int u = __builtin_bit_cast(unsigned int, f);
    u = (u + 0x7FFFu + ((u >> 16) & 1u)) >> 16;
    return (unsigned short)u;
}

__device__ __forceinline__ float gelu_exact(float v) {
    return 0.5f * v * (1.f + erff(v * 0.70710678118654752f));
}

// ---------------------------------------------------------------------------
// LayerNorm over last dim (384). One wave per row. BF16OUT picks dst type.
// ---------------------------------------------------------------------------
template <int BF16OUT>
__global__ void ln_kernel(const float* __restrict__ x, void* __restrict__ outp,
                          const float* __restrict__ g, const float* __restrict__ bt,
                          int mode) {
    const int row = blockIdx.x;
    const int lane = threadIdx.x;           // 64 threads
    const float* src;
    if (mode == 0)      src = x + (size_t)row * (197 * 384);
    else if (mode == 1) { int b = row / 196, n = row % 196; src = x + (size_t)(b * 197 + 1 + n) * 384; }
    else if (mode == 2) { int b = row / 196, n = row % 196; src = x + (size_t)((16 + b) * 197 + 1 + n) * 384; }
    else                src = x + (size_t)row * 384;

    float v[6];
    float s = 0.f, s2 = 0.f;
#pragma unroll
    for (int j = 0; j < 6; j++) {
        v[j] = src[lane + j * 64];
        s += v[j];
        s2 += v[j] * v[j];
    }
#pragma unroll
    for (int o = 32; o; o >>= 1) {
        s  += __shfl_xor(s, o);
        s2 += __shfl_xor(s2, o);
    }
    const float mu = s * (1.f / 384.f);
    const float var = s2 * (1.f / 384.f) - mu * mu;
    const float rs = 1.f / sqrtf(var + 1e-5f);
#pragma unroll
    for (int j = 0; j < 6; j++) {
        const int c = lane + j * 64;
        const float r = (v[j] - mu) * rs * g[c] + bt[c];
        if (BF16OUT) ((unsigned short*)outp)[(size_t)row * 384 + c] = f2bf(r);
        else         ((float*)outp)[(size_t)row * 384 + c] = r;
    }
}

// ---------------------------------------------------------------------------
// cls-path GEMM, latency-optimized (round 6: 140 -> ~5 µs class).
// ---------------------------------------------------------------------------
template <int M>
__global__ void gemm_cls(const float* __restrict__ A, const float* __restrict__ B,
                         const float* __restrict__ bias, float* __restrict__ C,
                         int N, int ldc) {
    __shared__ float sA[M * 384];
    __shared__ float red[4][M][64];
    const int t = threadIdx.x;
    const int tc = t & 63, ks = t >> 6;
    const int n = blockIdx.x * 64 + tc;
    for (int e = t; e < M * 384; e += 256) sA[e] = A[e];
    __syncthreads();
    float acc[M];
#pragma unroll
    for (int m = 0; m < M; m++) acc[m] = 0.f;
    const int k0 = ks * 96;
#pragma unroll 4
    for (int k = k0; k < k0 + 96; k++) {
        const float bv = B[(size_t)k * N + n];
#pragma unroll
        for (int m = 0; m < M; m++) acc[m] += sA[m * 384 + k] * bv;
    }
#pragma unroll
    for (int m = 0; m < M; m++) red[ks][m][tc] = acc[m];
    __syncthreads();
    if (ks == 0) {
#pragma unroll
        for (int m = 0; m < M; m++) {
            float s = red[0][m][tc] + red[1][m][tc] + red[2][m][tc] + red[3][m][tc];
            if (bias) s += bias[n];
            C[(size_t)m * ldc + n] = s;
        }
    }
}

// ---------------------------------------------------------------------------
// cls attention (verified)
// ---------------------------------------------------------------------------
__global__ void attn_cls_kernel(const float* __restrict__ qv, const float* __restrict__ kcls,
                                float* __restrict__ aflat, float* __restrict__ cls_pre) {
    const int b = blockIdx.x;
    const int t = threadIdx.x;  // 64
    __shared__ float kb[384];
    __shared__ float pl[60];
#pragma unroll
    for (int j = 0; j < 6; j++) kb[t + j * 64] = kcls[b * 384 + t + j * 64];
    __syncthreads();
    if (t < 60) {
        const int n = t / 6, h = t % 6;
        float acc = 0.f;
        for (int d = 0; d < 64; d++) acc += qv[n * 768 + h * 64 + d] * kb[h * 64 + d];
        pl[t] = acc * SCL;
    }
    __syncthreads();
    if (t < 6) {
        float m = -1e30f;
        for (int n = 0; n < 10; n++) m = fmaxf(m, pl[n * 6 + t]);
        float p[10], sum = 0.f;
        for (int n = 0; n < 10; n++) { p[n] = expf(pl[n * 6 + t] - m); sum += p[n]; }
        const float inv = 1.f / sum;
        for (int n = 0; n < 10; n++) {
            const float pr = p[n] * inv;
            pl[n * 6 + t] = pr;
            aflat[b * 60 + n * 6 + t] = pr;   // reference flat (n,h) order
        }
    }
    __syncthreads();
#pragma unroll
    for (int j = 0; j < 6; j++) {
        const int c = t + j * 64;
        const int h = c >> 6;
        float acc = 0.f;
        for (int n = 0; n < 10; n++) acc += pl[n * 6 + h] * qv[n * 768 + 384 + c];
        cls_pre[b * 384 + c] = acc;
    }
}

// ---------------------------------------------------------------------------
// Weight transpose-cast: Wt[n][k] = bf16(W[k][n]).
// wcast_t: grid (N/64, K/64). wcast3: 3 square 384x384 weights in one
// launch via blockIdx.z -> fused Wx_t[1152][384].
// ---------------------------------------------------------------------------
__global__ void wcast_t(const float* __restrict__ W, unsigned short* __restrict__ Wt,
                        int K, int N) {
    const int n0 = blockIdx.x * 64, k0 = blockIdx.y * 64;
    __shared__ unsigned short sT[64][72];
    const int t = threadIdx.x;
    for (int e = t; e < 4096; e += 256) {
        const int k = e >> 6, n = e & 63;
        sT[n][k] = f2bf(W[(size_t)(k0 + k) * N + n0 + n]);
    }
    __syncthreads();
    for (int e = t; e < 512; e += 256) {
        const int n = e >> 3, ch = e & 7;
        *(uint4*)&Wt[(size_t)(n0 + n) * K + k0 + ch * 8] = *(uint4*)&sT[n][ch * 8];
    }
}

__global__ void wcast3(const float* __restrict__ Wa, const float* __restrict__ Wb,
                       const float* __restrict__ Wc, unsigned short* __restrict__ Wt) {
    const float* W = blockIdx.z == 0 ? Wa : (blockIdx.z == 1 ? Wb : Wc);
    unsigned short* dst = Wt + (size_t)blockIdx.z * 384 * 384;
    const int n0 = blockIdx.x * 64, k0 = blockIdx.y * 64;
    __shared__ unsigned short sT[64][72];
    const int t = threadIdx.x;
    for (int e = t; e < 4096; e += 256) {
        const int k = e >> 6, n = e & 63;
        sT[n][k] = f2bf(W[(size_t)(k0 + k) * 384 + n0 + n]);
    }
    __syncthreads();
    for (int e = t; e < 512; e += 256) {
        const int n = e >> 3, ch = e & 7;
        *(uint4*)&dst[(size_t)(n0 + n) * 384 + k0 + ch * 8] = *(uint4*)&sT[n][ch * 8];
    }
}

// ---------------------------------------------------------------------------
// bf16 MFMA GEMM: C = epilogue(A @ Bt^T). A [M][K] bf16, Bt [N][K] bf16.
// BM=64, BN=128, BK=64, 256 threads. Output row stride = N (so a fused
// N=1152 launch writes the packed P[row][1152] layout directly).
// EPI: 0 bf16-out plain; 1 fp32 +bias +res REMAP (row->row+row/196+1);
//      2 bf16 +bias +GELU; 3 fp32 +bias +res.
// ---------------------------------------------------------------------------
template <int EPI>
__launch_bounds__(256)
__global__ void gemm_mfma(const unsigned short* __restrict__ A,
                          const unsigned short* __restrict__ Bt,
                          const float* __restrict__ bias, const float* __restrict__ res,
                          void* __restrict__ Cout, int M, int N, int K) {
    const int m0 = blockIdx.y * 64, n0 = blockIdx.x * 128;
    const int t = threadIdx.x;
    const int w = t >> 6, l = t & 63;
    const int lr = l & 15, lk = l >> 4;
    const int wr = w >> 1, wc = w & 1;

    __shared__ unsigned short sA[64][72];
    __shared__ unsigned short sB[128][72];

    f32x4 acc[2][4];
#pragma unroll
    for (int mi = 0; mi < 2; mi++)
#pragma unroll
        for (int nj = 0; nj < 4; nj++) acc[mi][nj] = (f32x4){0.f, 0.f, 0.f, 0.f};

    for (int k0 = 0; k0 < K; k0 += 64) {
        for (int e = t; e < 512; e += 256) {
            const int r = e >> 3, ch = e & 7;
            uint4 v = make_uint4(0, 0, 0, 0);
            const int row = m0 + r;
            if (row < M) v = *(const uint4*)(A + (size_t)row * K + k0 + ch * 8);
            *(uint4*)&sA[r][ch * 8] = v;
        }
        for (int e = t; e < 1024; e += 256) {
            const int r = e >> 3, ch = e & 7;
            *(uint4*)&sB[r][ch * 8] = *(const uint4*)(Bt + (size_t)(n0 + r) * K + k0 + ch * 8);
        }
        __syncthreads();
#pragma unroll
        for (int kc = 0; kc < 2; kc++) {
            bf16x8 af[2], bfr[4];
#pragma unroll
            for (int mi = 0; mi < 2; mi++)
                af[mi] = *(const bf16x8*)&sA[wr * 32 + mi * 16 + lr][kc * 32 + lk * 8];
#pragma unroll
            for (int nj = 0; nj < 4; nj++)
                bfr[nj] = *(const bf16x8*)&sB[wc * 64 + nj * 16 + lr][kc * 32 + lk * 8];
#pragma unroll
            for (int mi = 0; mi < 2; mi++)
#pragma unroll
                for (int nj = 0; nj < 4; nj++)
                    acc[mi][nj] = MFMA16(af[mi], bfr[nj], acc[mi][nj]);
        }
        __syncthreads();
    }

#pragma unroll
    for (int mi = 0; mi < 2; mi++)
#pragma unroll
        for (int nj = 0; nj < 4; nj++) {
            const int col = n0 + wc * 64 + nj * 16 + lr;
#pragma unroll
            for (int i = 0; i < 4; i++) {
                const int row = m0 + wr * 32 + mi * 16 + lk * 4 + i;
                if (row >= M) continue;
                float v = acc[mi][nj][i];
                if (EPI == 0) {
                    ((unsigned short*)Cout)[(size_t)row * N + col] = f2bf(v);
                } else if (EPI == 1) {
                    const int crow = row + row / 196 + 1;
                    v += bias[col] + res[(size_t)crow * N + col];
                    ((float*)Cout)[(size_t)crow * N + col] = v;
                } else if (EPI == 2) {
                    ((unsigned short*)Cout)[(size_t)row * N + col] = f2bf(gelu_exact(v + bias[col]));
                } else {
                    v += bias[col] + res[(size_t)row * N + col];
                    ((float*)Cout)[(size_t)row * N + col] = v;
                }
            }
        }
}

// ===========================================================================
// MFMA chain, stage A:  Zt[b,h,c][d][m] = sum_k relu(SCL*k2_c[m]·q2_b[k]) * vr_b[k,d]
// (verified round 3; takes row strides for the fused P layout)
// ===========================================================================
__global__ __launch_bounds__(256, 1)
void rz_kernel(const unsigned short* __restrict__ Q2b, const unsigned short* __restrict__ K2b,
               const unsigned short* __restrict__ VRb, unsigned short* __restrict__ Zt,
               int sq, int sk, int sv) {
    const int c = blockIdx.x, h = blockIdx.y, b = blockIdx.z;
    const int t = threadIdx.x;
    const int w = t >> 6, l = t & 63;
    const int lr = l & 15;
    const int lk = l >> 4;

    __shared__ unsigned short sm[78208];
    unsigned short* sQ2 = sm;                     // [208][72]
    unsigned short* sVT = sm;                     // [64][232]  alias, phase 2+
    unsigned short* sK2 = sm + 14976;             // [208][72]
    unsigned short* sR  = sm + 29952;             // [208][232]

    const unsigned short* q2src = Q2b + (size_t)(b * 196) * sq + h * 64;
    const unsigned short* k2src = K2b + (size_t)(c * 196) * sk + h * 64;
    for (int e = t; e < 208 * 8; e += 256) {
        const int r = e >> 3, ch = e & 7;
        uint4 v = make_uint4(0, 0, 0, 0);
        if (r < 196) v = *(const uint4*)(q2src + (size_t)r * sq + ch * 8);
        *(uint4*)&sQ2[r * 72 + ch * 8] = v;
    }
    for (int e = t; e < 208 * 8; e += 256) {
        const int r = e >> 3, ch = e & 7;
        uint4 v = make_uint4(0, 0, 0, 0);
        if (r < 196) v = *(const uint4*)(k2src + (size_t)r * sk + ch * 8);
        *(uint4*)&sK2[r * 72 + ch * 8] = v;
    }
    for (int e = t; e < 208 * 16; e += 256) sR[(e >> 4) * 232 + 208 + (e & 15)] = 0;
    __syncthreads();

    for (int tt = w; tt < 169; tt += 4) {
        const int mt = tt / 13, kt = tt % 13;
        f32x4 acc = {0.f, 0.f, 0.f, 0.f};
        bf16x8 a0 = *(const bf16x8*)&sK2[(mt * 16 + lr) * 72 + lk * 8];
        bf16x8 b0 = *(const bf16x8*)&sQ2[(kt * 16 + lr) * 72 + lk * 8];
        acc = MFMA16(a0, b0, acc);
        bf16x8 a1 = *(const bf16x8*)&sK2[(mt * 16 + lr) * 72 + 32 + lk * 8];
        bf16x8 b1 = *(const bf16x8*)&sQ2[(kt * 16 + lr) * 72 + 32 + lk * 8];
        acc = MFMA16(a1, b1, acc);
        const int rrow = mt * 16 + lk * 4, rcol = kt * 16 + lr;
#pragma unroll
        for (int i = 0; i < 4; i++)
            sR[(rrow + i) * 232 + rcol] = f2bf(fmaxf(0.f, SCL * acc[i]));
    }
    __syncthreads();

    const unsigned short* vrsrc = VRb + (size_t)(b * 196) * sv + h * 64;
    for (int e = t; e < 196 * 8; e += 256) {
        const int kk = e >> 3, ch = e & 7;
        uint4 v = *(const uint4*)(vrsrc + (size_t)kk * sv + ch * 8);
        unsigned short vs[8]; *(uint4*)vs = v;
#pragma unroll
        for (int j = 0; j < 8; j++) sVT[(ch * 8 + j) * 232 + kk] = vs[j];
    }
    for (int e = t; e < 64 * 36; e += 256) sVT[(e / 36) * 232 + 196 + (e % 36)] = 0;
    __syncthreads();

    unsigned short* zdst = Zt + ((((size_t)(b * 6 + h)) * 10 + c) * 64) * 208;
    for (int tt = w; tt < 52; tt += 4) {
        const int mt = tt >> 2, dt = tt & 3;
        f32x4 acc = {0.f, 0.f, 0.f, 0.f};
#pragma unroll
        for (int kc = 0; kc < 7; kc++) {
            bf16x8 a = *(const bf16x8*)&sR[(mt * 16 + lr) * 232 + kc * 32 + lk * 8];
            bf16x8 bb = *(const bf16x8*)&sVT[(dt * 16 + lr) * 232 + kc * 32 + lk * 8];
            acc = MFMA16(a, bb, acc);
        }
        unsigned short p[4];
#pragma unroll
        for (int i = 0; i < 4; i++) p[i] = f2bf(acc[i]);
        *(uint2*)&zdst[(size_t)(dt * 16 + lr) * 208 + mt * 16 + lk * 4] = *(uint2*)p;
    }
}

// ===========================================================================
// MFMA chain, stage B — occupancy-restructured (round 7 design, layout-fixed).
//   - wave w owns n-tile w: Q in registers (c-invariant), sL wave-local,
//     KH staged in two halves -> LDS 75.5 KB -> 2 blocks/CU, grid 384.
// ===========================================================================
__global__ __launch_bounds__(256)
void yz_kernel(const unsigned short* __restrict__ QHb, const unsigned short* __restrict__ KHb,
               const unsigned short* __restrict__ Zt, const float* __restrict__ aflat,
               unsigned short* __restrict__ rect) {
    const int ns = blockIdx.x, h = blockIdx.y, b = blockIdx.z;
    const int n0 = ns * 49;
    const int t = threadIdx.x;
    const int w = t >> 6, l = t & 63;
    const int lr = l & 15, lk = l >> 4;

    __shared__ unsigned short sKH[112 * 72];   // 16,128 B (KH m-half)
    __shared__ unsigned short sZT[64 * 232];   // 29,696 B
    __shared__ unsigned short sL[64 * 232];    // 29,696 B -> total 75,520 B

    // zero pad cols 208..231 once (PV K reaches 223)
    for (int e = t; e < 64 * 24; e += 256) {
        sZT[(e / 24) * 232 + 208 + (e % 24)] = 0;
        sL [(e / 24) * 232 + 208 + (e % 24)] = 0;
    }

    // Q fragments in registers: wave w rows n0 + w*16 + lr, cols h*64 + kc*32 + lk*8
    bf16x8 qf[2];
    {
        const int rel = w * 16 + lr;
        if (rel < 49) {
            const unsigned short* qsrc = QHb + (size_t)(b * 196 + n0 + rel) * 1152 + h * 64;
            qf[0] = *(const bf16x8*)(qsrc + lk * 8);
            qf[1] = *(const bf16x8*)(qsrc + 32 + lk * 8);
        } else {
            qf[0] = (bf16x8){0, 0, 0, 0, 0, 0, 0, 0};
            qf[1] = (bf16x8){0, 0, 0, 0, 0, 0, 0, 0};
        }
    }

    f32x4 y[4];
#pragma unroll
    for (int i = 0; i < 4; i++) y[i] = (f32x4){0.f, 0.f, 0.f, 0.f};
    __syncthreads();   // pad zeros visible

    for (int c = 0; c < 10; c++) {
        // A: stage ZT(c) + KH(c) rows 0..111
        const unsigned short* zsrc = Zt + ((((size_t)(b * 6 + h)) * 10 + c) * 64) * 208;
        for (int e = t; e < 64 * 26; e += 256) {
            const int d = e / 26, mc = e % 26;
            *(uint4*)&sZT[d * 232 + mc * 8] = *(const uint4*)(zsrc + (size_t)d * 208 + mc * 8);
        }
        for (int e = t; e < 112 * 8; e += 256) {
            const int r = e >> 3, ch = e & 7;
            *(uint4*)&sKH[r * 72 + ch * 8] =
                *(const uint4*)(KHb + (size_t)(c * 196 + r) * 768 + h * 64 + ch * 8);
        }
        const float wc = aflat[b * 60 + h * 10 + c];
        __syncthreads();                       // bar1: staging visible
        // B: L half1 (mt 0..6) -> wave-local sL rows
#pragma unroll
        for (int mt = 0; mt < 7; mt++) {
            f32x4 acc = {0.f, 0.f, 0.f, 0.f};
            bf16x8 b0 = *(const bf16x8*)&sKH[(mt * 16 + lr) * 72 + lk * 8];
            acc = MFMA16(qf[0], b0, acc);
            bf16x8 b1 = *(const bf16x8*)&sKH[(mt * 16 + lr) * 72 + 32 + lk * 8];
            acc = MFMA16(qf[1], b1, acc);
            const int lrow = w * 16 + lk * 4, lcol = mt * 16 + lr;
#pragma unroll
            for (int i = 0; i < 4; i++)
                sL[(lrow + i) * 232 + lcol] = f2bf(wc * fmaxf(0.f, -SCL * acc[i]));
        }
        __syncthreads();                       // bar2: all waves done with KH half1
        // C: stage KH rows 112..207 (rows >=196 zero)
        for (int e = t; e < 96 * 8; e += 256) {
            const int r = e >> 3, ch = e & 7;
            uint4 v = make_uint4(0, 0, 0, 0);
            if (112 + r < 196)
                v = *(const uint4*)(KHb + (size_t)(c * 196 + 112 + r) * 768 + h * 64 + ch * 8);
            *(uint4*)&sKH[r * 72 + ch * 8] = v;
        }
        __syncthreads();                       // bar3
        // D: L half2 (mt 7..12)
#pragma unroll
        for (int mt = 7; mt < 13; mt++) {
            f32x4 acc = {0.f, 0.f, 0.f, 0.f};
            bf16x8 b0 = *(const bf16x8*)&sKH[((mt - 7) * 16 + lr) * 72 + lk * 8];
            acc = MFMA16(qf[0], b0, acc);
            bf16x8 b1 = *(const bf16x8*)&sKH[((mt - 7) * 16 + lr) * 72 + 32 + lk * 8];
            acc = MFMA16(qf[1], b1, acc);
            const int lrow = w * 16 + lk * 4, lcol = mt * 16 + lr;
#pragma unroll
            for (int i = 0; i < 4; i++)
                sL[(lrow + i) * 232 + lcol] = f2bf(wc * fmaxf(0.f, -SCL * acc[i]));
        }
        // E: PV (sL rows wave-local; sZT stable since bar1) — no barrier needed
#pragma unroll
        for (int dt = 0; dt < 4; dt++) {
            f32x4 acc = y[dt];
#pragma unroll
            for (int mc = 0; mc < 7; mc++) {
                bf16x8 a  = *(const bf16x8*)&sL[(w * 16 + lr) * 232 + mc * 32 + lk * 8];
                bf16x8 bb = *(const bf16x8*)&sZT[(dt * 16 + lr) * 232 + mc * 32 + lk * 8];
                acc = MFMA16(a, bb, acc);
            }
            y[dt] = acc;
        }
        __syncthreads();                       // bar4: sZT/sKH free for next c
    }

    // write out: wave w rows n0 + w*16 + lk*4 + i (rel<49), cols dt*16+lr
#pragma unroll
    for (int dt = 0; dt < 4; dt++)
#pragma unroll
        for (int i = 0; i < 4; i++) {
            const int rel = w * 16 + lk * 4 + i;
            if (rel < 49)
                rect[(((size_t)(b * 6 + h)) * 196 + n0 + rel) * 64 + dt * 16 + lr] = f2bf(y[dt][i]);
        }
}

// ---------------------------------------------------------------------------
// Copy anchors verbatim.
// ---------------------------------------------------------------------------
__global__ void copy_anchors(const float* __restrict__ x, float* __restrict__ out) {
    const int e = blockIdx.x * 256 + threadIdx.x;
    if (e < 189120) {
        const int base = 16 * 197 * 384 / 4;
        ((float4*)out)[base + e] = ((const float4*)x)[base + e];
    }
}

// ---------------------------------------------------------------------------
// kernel_launch. Workspace in f32 units, total 12,655,296 f = 50.6 MB.
// ROUND-7 BUG FIXED HERE: xx was at 3,869,376, overlapping rect_bf
// [3,568,320 .. 4,170,432) -> steps 8/9 clobbered rect while reading -> NaN.
// Layout now: Px | Pa | rect | xx | Wx_t | Wr_t | W1_t | W2_t | Zt (hdn/G
// alias Zt, dead after yz). No overlaps among live ranges.
// ---------------------------------------------------------------------------
extern "C" void kernel_launch(void* const* d_in, const int* in_sizes, int n_in,
                              void* d_out, int out_size, void* d_ws, size_t ws_size,
                              hipStream_t stream) {
    (void)in_sizes; (void)n_in; (void)out_size; (void)ws_size;
    const float* x       = (const float*)d_in[0];
    const float* Wqv     = (const float*)d_in[1];
    const float* Wk      = (const float*)d_in[2];
    const float* Wq_proj = (const float*)d_in[3];
    const float* bq_proj = (const float*)d_in[4];
    const float* Wqk     = (const float*)d_in[5];
    const float* Wqk2    = (const float*)d_in[6];
    const float* Wv      = (const float*)d_in[7];
    const float* Wr_proj = (const float*)d_in[8];
    const float* br_proj = (const float*)d_in[9];
    const float* g1      = (const float*)d_in[10];
    const float* b1      = (const float*)d_in[11];
    const float* g2      = (const float*)d_in[12];
    const float* b2      = (const float*)d_in[13];
    const float* g3      = (const float*)d_in[14];
    const float* b3      = (const float*)d_in[15];
    const float* W1      = (const float*)d_in[16];
    const float* bm1     = (const float*)d_in[17];
    const float* W2      = (const float*)d_in[18];
    const float* bm2     = (const float*)d_in[19];

    float* ws = (float*)d_ws;
    float* n1      = ws;                                       //      9,984
    float* qv      = ws + 9984;                                //      7,680
    float* kcls    = ws + 17664;                               //      6,144
    float* aflat   = ws + 23808;                               //        960
    float* cls_pre = ws + 24768;                               //      6,144
    unsigned short* n2x_bf  = (unsigned short*)(ws + 30912);   // 3136x384 bf16  [ends   633,024]
    unsigned short* n2a_bf  = (unsigned short*)(ws + 633024);  // 1960x384 bf16  [ends 1,009,344]
    unsigned short* Px      = (unsigned short*)(ws + 1009344); // 3136x1152 bf16 [ends 2,815,680]
    unsigned short* Pa      = (unsigned short*)(ws + 2815680); // 1960x768 bf16  [ends 3,568,320]
    unsigned short* rect_bf = (unsigned short*)(ws + 3568320); // 3136x384 bf16  [ends 4,170,432]
    float* xx               = ws + 4170432;                    // 16x197x384 f32 [ends 5,380,800]
    unsigned short* Wx_t    = (unsigned short*)(ws + 5380800); // 1152x384 bf16  [ends 5,601,984]
    unsigned short* Wr_t    = (unsigned short*)(ws + 5601984); // 384x384 bf16   [ends 5,675,712]
    unsigned short* W1_t    = (unsigned short*)(ws + 5675712); // 1536x384 bf16  [ends 5,970,624]
    unsigned short* W2_t    = (unsigned short*)(ws + 5970624); // 384x1536 bf16  [ends 6,265,536]
    unsigned short* Zt      = (unsigned short*)(ws + 6265536); // 96*10*64*208   [ends 12,655,296]
    unsigned short* hdn_bf  = (unsigned short*)(ws + 6265536); // alias Zt (dead after yz)
    unsigned short* G_bf    = (unsigned short*)(ws + 6870720); // alias Zt region
    float* outf = (float*)d_out;

    // column-slice views of the fused projection buffers
    unsigned short* QHb = Px;           // stride 1152
    unsigned short* Q2b = Px + 384;
    unsigned short* VRb = Px + 768;
    unsigned short* KHb = Pa;           // stride 768
    unsigned short* K2b = Pa + 384;

    // 0. weight transpose-casts
    wcast3<<<dim3(6, 6, 3), 256, 0, stream>>>(Wqk, Wqk2, Wv, Wx_t);
    wcast_t<<<dim3(6, 6),  256, 0, stream>>>(Wr_proj, Wr_t, 384, 384);
    wcast_t<<<dim3(24, 6), 256, 0, stream>>>(W1, W1_t, 384, 1536);
    wcast_t<<<dim3(6, 24), 256, 0, stream>>>(W2, W2_t, 1536, 384);
    // 1. LN cls tokens (fp32 out)
    ln_kernel<0><<<26, 64, 0, stream>>>(x, n1, g1, b1, 0);
    // 2. qv / kcls (latency-optimized cls GEMMs)
    gemm_cls<10><<<12, 256, 0, stream>>>(n1 + 16 * 384, Wqv, nullptr, qv, 768, 768);
    gemm_cls<16><<<6, 256, 0, stream>>>(n1, Wk, nullptr, kcls, 384, 384);
    // 3. cls attention
    attn_cls_kernel<<<16, 64, 0, stream>>>(qv, kcls, aflat, cls_pre);
    // 4. LN image tokens (bf16 out)
    ln_kernel<1><<<3136, 64, 0, stream>>>(x, n2x_bf, g2, b2, 1);
    ln_kernel<1><<<1960, 64, 0, stream>>>(x, n2a_bf, g2, b2, 2);
    // 5. fused head projections: Px = n2x @ [Wqk|Wqk2|Wv]; Pa = n2a @ [Wqk|Wqk2]
    gemm_mfma<0><<<dim3(9, 49), 256, 0, stream>>>(n2x_bf, Wx_t, nullptr, nullptr, Px, 3136, 1152, 384);
    gemm_mfma<0><<<dim3(6, 31), 256, 0, stream>>>(n2a_bf, Wx_t, nullptr, nullptr, Pa, 1960, 768, 384);
    // 6. chain stage A
    rz_kernel<<<dim3(10, 6, 16), 256, 0, stream>>>(Q2b, K2b, VRb, Zt, 1152, 768, 1152);
    // 7. chain stage B -> rect bf16 (reshape layout)
    yz_kernel<<<dim3(4, 6, 16), 256, 0, stream>>>(QHb, KHb, Zt, aflat, rect_bf);
    // 8. cls_out -> xx token 0
    gemm_cls<16><<<6, 256, 0, stream>>>(cls_pre, Wq_proj, bq_proj, xx, 384, 197 * 384);
    // 9. xx[:,1:] = rect @ Wr_proj + br + x_im  (remapped rows)
    gemm_mfma<1><<<dim3(3, 49), 256, 0, stream>>>(rect_bf, Wr_t, br_proj, x, xx, 3136, 384, 384);
    // 10. LN3 (bf16 out into hdn)
    ln_kernel<1><<<3152, 64, 0, stream>>>(xx, hdn_bf, g3, b3, 3);
    // 11. MLP up + GELU -> bf16 G
    gemm_mfma<2><<<dim3(12, 50), 256, 0, stream>>>(hdn_bf, W1_t, bm1, nullptr, G_bf, 3152, 1536, 384);
    // 12. MLP down + bias + residual -> out rows 0..3151
    gemm_mfma<3><<<dim3(3, 50), 256, 0, stream>>>(G_bf, W2_t, bm2, xx, outf, 3152, 384, 1536);
    // 13. anchors pass-through
    copy_anchors<<<739, 256, 0, stream>>>(x, outf);
}

// Round 9
// 470.147 us; speedup vs baseline: 4.6122x; 1.0708x over previous
//
#include <hip/hip_runtime.h>
#include <hip/hip_bf16.h>
#include <math.h>

#define SCL 0.125f

typedef float f32x4 __attribute__((ext_vector_type(4)));
typedef short bf16x8 __attribute__((ext_vector_type(8)));   // 8 bf16 in 4 VGPRs
#define MFMA16(a, b, c) __builtin_amdgcn_mfma_f32_16x16x32_bf16((a), (b), (c), 0, 0, 0)

// f32 -> bf16 round-to-nearest-even
__device__ __forceinline__ unsigned short f2bf(float f) {
    unsigned int u = __builtin_bit_cast(unsigned int, f);
    u = (u + 0x7FFFu + ((u >> 16) & 1u)) >> 16;
    return (unsigned short)u;
}

__device__ __forceinline__ float gelu_exact(float v) {
    return 0.5f * v * (1.f + erff(v * 0.70710678118654752f));
}

// ---------------------------------------------------------------------------
// LayerNorm over last dim (384). One wave per row. BF16OUT picks dst type.
// mode 4: fused image LN (rows 0..3135 = xs, 3136..5095 = anchors) -> one
// launch instead of two (n2x_bf / n2a_bf are contiguous in ws).
// ---------------------------------------------------------------------------
template <int BF16OUT>
__global__ void ln_kernel(const float* __restrict__ x, void* __restrict__ outp,
                          const float* __restrict__ g, const float* __restrict__ bt,
                          int mode) {
    const int row = blockIdx.x;
    const int lane = threadIdx.x;           // 64 threads
    const float* src;
    if (mode == 0)      src = x + (size_t)row * (197 * 384);
    else if (mode == 4) {
        if (row < 3136) { int b = row / 196, n = row % 196; src = x + (size_t)(b * 197 + 1 + n) * 384; }
        else { int rr = row - 3136; int b = rr / 196, n = rr % 196; src = x + (size_t)((16 + b) * 197 + 1 + n) * 384; }
    }
    else                src = x + (size_t)row * 384;

    float v[6];
    float s = 0.f, s2 = 0.f;
#pragma unroll
    for (int j = 0; j < 6; j++) {
        v[j] = src[lane + j * 64];
        s += v[j];
        s2 += v[j] * v[j];
    }
#pragma unroll
    for (int o = 32; o; o >>= 1) {
        s  += __shfl_xor(s, o);
        s2 += __shfl_xor(s2, o);
    }
    const float mu = s * (1.f / 384.f);
    const float var = s2 * (1.f / 384.f) - mu * mu;
    const float rs = 1.f / sqrtf(var + 1e-5f);
#pragma unroll
    for (int j = 0; j < 6; j++) {
        const int c = lane + j * 64;
        const float r = (v[j] - mu) * rs * g[c] + bt[c];
        if (BF16OUT) ((unsigned short*)outp)[(size_t)row * 384 + c] = f2bf(r);
        else         ((float*)outp)[(size_t)row * 384 + c] = r;
    }
}

// ---------------------------------------------------------------------------
// cls-path GEMM, latency-optimized (round 6: 140 -> ~5 µs class).
// ---------------------------------------------------------------------------
template <int M>
__global__ void gemm_cls(const float* __restrict__ A, const float* __restrict__ B,
                         const float* __restrict__ bias, float* __restrict__ C,
                         int N, int ldc) {
    __shared__ float sA[M * 384];
    __shared__ float red[4][M][64];
    const int t = threadIdx.x;
    const int tc = t & 63, ks = t >> 6;
    const int n = blockIdx.x * 64 + tc;
    for (int e = t; e < M * 384; e += 256) sA[e] = A[e];
    __syncthreads();
    float acc[M];
#pragma unroll
    for (int m = 0; m < M; m++) acc[m] = 0.f;
    const int k0 = ks * 96;
#pragma unroll 4
    for (int k = k0; k < k0 + 96; k++) {
        const float bv = B[(size_t)k * N + n];
#pragma unroll
        for (int m = 0; m < M; m++) acc[m] += sA[m * 384 + k] * bv;
    }
#pragma unroll
    for (int m = 0; m < M; m++) red[ks][m][tc] = acc[m];
    __syncthreads();
    if (ks == 0) {
#pragma unroll
        for (int m = 0; m < M; m++) {
            float s = red[0][m][tc] + red[1][m][tc] + red[2][m][tc] + red[3][m][tc];
            if (bias) s += bias[n];
            C[(size_t)m * ldc + n] = s;
        }
    }
}

// ---------------------------------------------------------------------------
// cls attention (verified)
// ---------------------------------------------------------------------------
__global__ void attn_cls_kernel(const float* __restrict__ qv, const float* __restrict__ kcls,
                                float* __restrict__ aflat, float* __restrict__ cls_pre) {
    const int b = blockIdx.x;
    const int t = threadIdx.x;  // 64
    __shared__ float kb[384];
    __shared__ float pl[60];
#pragma unroll
    for (int j = 0; j < 6; j++) kb[t + j * 64] = kcls[b * 384 + t + j * 64];
    __syncthreads();
    if (t < 60) {
        const int n = t / 6, h = t % 6;
        float acc = 0.f;
        for (int d = 0; d < 64; d++) acc += qv[n * 768 + h * 64 + d] * kb[h * 64 + d];
        pl[t] = acc * SCL;
    }
    __syncthreads();
    if (t < 6) {
        float m = -1e30f;
        for (int n = 0; n < 10; n++) m = fmaxf(m, pl[n * 6 + t]);
        float p[10], sum = 0.f;
        for (int n = 0; n < 10; n++) { p[n] = expf(pl[n * 6 + t] - m); sum += p[n]; }
        const float inv = 1.f / sum;
        for (int n = 0; n < 10; n++) {
            const float pr = p[n] * inv;
            pl[n * 6 + t] = pr;
            aflat[b * 60 + n * 6 + t] = pr;   // reference flat (n,h) order
        }
    }
    __syncthreads();
#pragma unroll
    for (int j = 0; j < 6; j++) {
        const int c = t + j * 64;
        const int h = c >> 6;
        float acc = 0.f;
        for (int n = 0; n < 10; n++) acc += pl[n * 6 + h] * qv[n * 768 + 384 + c];
        cls_pre[b * 384 + c] = acc;
    }
}

// ---------------------------------------------------------------------------
// Weight transpose-cast: Wt[n][k] = bf16(W[k][n]).
// ---------------------------------------------------------------------------
__global__ void wcast_t(const float* __restrict__ W, unsigned short* __restrict__ Wt,
                        int K, int N) {
    const int n0 = blockIdx.x * 64, k0 = blockIdx.y * 64;
    __shared__ unsigned short sT[64][72];
    const int t = threadIdx.x;
    for (int e = t; e < 4096; e += 256) {
        const int k = e >> 6, n = e & 63;
        sT[n][k] = f2bf(W[(size_t)(k0 + k) * N + n0 + n]);
    }
    __syncthreads();
    for (int e = t; e < 512; e += 256) {
        const int n = e >> 3, ch = e & 7;
        *(uint4*)&Wt[(size_t)(n0 + n) * K + k0 + ch * 8] = *(uint4*)&sT[n][ch * 8];
    }
}

__global__ void wcast3(const float* __restrict__ Wa, const float* __restrict__ Wb,
                       const float* __restrict__ Wc, unsigned short* __restrict__ Wt) {
    const float* W = blockIdx.z == 0 ? Wa : (blockIdx.z == 1 ? Wb : Wc);
    unsigned short* dst = Wt + (size_t)blockIdx.z * 384 * 384;
    const int n0 = blockIdx.x * 64, k0 = blockIdx.y * 64;
    __shared__ unsigned short sT[64][72];
    const int t = threadIdx.x;
    for (int e = t; e < 4096; e += 256) {
        const int k = e >> 6, n = e & 63;
        sT[n][k] = f2bf(W[(size_t)(k0 + k) * 384 + n0 + n]);
    }
    __syncthreads();
    for (int e = t; e < 512; e += 256) {
        const int n = e >> 3, ch = e & 7;
        *(uint4*)&dst[(size_t)(n0 + n) * 384 + k0 + ch * 8] = *(uint4*)&sT[n][ch * 8];
    }
}

// ---------------------------------------------------------------------------
// bf16 MFMA GEMM: C = epilogue(A @ Bt^T). A [M][K] bf16, Bt [N][K] bf16.
// BM=64, BN=128, BK=64, 256 threads.
// EPI: 0 bf16-out plain; 1 fp32 +bias +res REMAP (row->row+row/196+1);
//      2 bf16 +bias +GELU; 3 fp32 +bias +res.
// ---------------------------------------------------------------------------
template <int EPI>
__launch_bounds__(256)
__global__ void gemm_mfma(const unsigned short* __restrict__ A,
                          const unsigned short* __restrict__ Bt,
                          const float* __restrict__ bias, const float* __restrict__ res,
                          void* __restrict__ Cout, int M, int N, int K) {
    const int m0 = blockIdx.y * 64, n0 = blockIdx.x * 128;
    const int t = threadIdx.x;
    const int w = t >> 6, l = t & 63;
    const int lr = l & 15, lk = l >> 4;
    const int wr = w >> 1, wc = w & 1;

    __shared__ unsigned short sA[64][72];
    __shared__ unsigned short sB[128][72];

    f32x4 acc[2][4];
#pragma unroll
    for (int mi = 0; mi < 2; mi++)
#pragma unroll
        for (int nj = 0; nj < 4; nj++) acc[mi][nj] = (f32x4){0.f, 0.f, 0.f, 0.f};

    for (int k0 = 0; k0 < K; k0 += 64) {
        for (int e = t; e < 512; e += 256) {
            const int r = e >> 3, ch = e & 7;
            uint4 v = make_uint4(0, 0, 0, 0);
            const int row = m0 + r;
            if (row < M) v = *(const uint4*)(A + (size_t)row * K + k0 + ch * 8);
            *(uint4*)&sA[r][ch * 8] = v;
        }
        for (int e = t; e < 1024; e += 256) {
            const int r = e >> 3, ch = e & 7;
            *(uint4*)&sB[r][ch * 8] = *(const uint4*)(Bt + (size_t)(n0 + r) * K + k0 + ch * 8);
        }
        __syncthreads();
#pragma unroll
        for (int kc = 0; kc < 2; kc++) {
            bf16x8 af[2], bfr[4];
#pragma unroll
            for (int mi = 0; mi < 2; mi++)
                af[mi] = *(const bf16x8*)&sA[wr * 32 + mi * 16 + lr][kc * 32 + lk * 8];
#pragma unroll
            for (int nj = 0; nj < 4; nj++)
                bfr[nj] = *(const bf16x8*)&sB[wc * 64 + nj * 16 + lr][kc * 32 + lk * 8];
#pragma unroll
            for (int mi = 0; mi < 2; mi++)
#pragma unroll
                for (int nj = 0; nj < 4; nj++)
                    acc[mi][nj] = MFMA16(af[mi], bfr[nj], acc[mi][nj]);
        }
        __syncthreads();
    }

#pragma unroll
    for (int mi = 0; mi < 2; mi++)
#pragma unroll
        for (int nj = 0; nj < 4; nj++) {
            const int col = n0 + wc * 64 + nj * 16 + lr;
#pragma unroll
            for (int i = 0; i < 4; i++) {
                const int row = m0 + wr * 32 + mi * 16 + lk * 4 + i;
                if (row >= M) continue;
                float v = acc[mi][nj][i];
                if (EPI == 0) {
                    ((unsigned short*)Cout)[(size_t)row * N + col] = f2bf(v);
                } else if (EPI == 1) {
                    const int crow = row + row / 196 + 1;
                    v += bias[col] + res[(size_t)crow * N + col];
                    ((float*)Cout)[(size_t)crow * N + col] = v;
                } else if (EPI == 2) {
                    ((unsigned short*)Cout)[(size_t)row * N + col] = f2bf(gelu_exact(v + bias[col]));
                } else {
                    v += bias[col] + res[(size_t)row * N + col];
                    ((float*)Cout)[(size_t)row * N + col] = v;
                }
            }
        }
}

// ===========================================================================
// MFMA chain, stage A — v2, occupancy-restructured (round 8: 72 µs at
// 153 KB LDS = 1 block/CU, MfmaUtil 5.6%).
//   Zt[b,h,c][d][m] = sum_k relu(SCL * k2_c[m]·q2_b[k]) * vr_b[k,d]
//   - q2 fragments in REGISTERS (26 x bf16x8, loaded once; kills sQ2/sK2)
//   - wave w owns m-tiles {w, w+4, ...}: S strip -> relu -> wave-private
//     sR tile [16][232] -> Z tile immediately (fused; no full-R matrix)
//   - LDS 59.4 KB -> 2 blocks/CU; ONE barrier total (after sVT staging)
//   - zero semantics as v1: pad fragments zeroed -> R rows/cols>=196 = 0
//     -> Zt pad cols zero (yz contracts over them harmlessly)
// ===========================================================================
__global__ __launch_bounds__(256, 2)
void rz_kernel(const unsigned short* __restrict__ Q2b, const unsigned short* __restrict__ K2b,
               const unsigned short* __restrict__ VRb, unsigned short* __restrict__ Zt,
               int sq, int sk, int sv) {
    const int c = blockIdx.x, h = blockIdx.y, b = blockIdx.z;
    const int t = threadIdx.x;
    const int w = t >> 6, l = t & 63;
    const int lr = l & 15, lk = l >> 4;

    __shared__ unsigned short sVT[64 * 232];        // vr^T [d][k], 29,696 B
    __shared__ unsigned short sR[4 * 16 * 232];     // per-wave R tile, 29,696 B
    unsigned short* sRw = sR + w * (16 * 232);

    // stage vr^T (scatter) + zero pad cols 196..231
    const unsigned short* vrsrc = VRb + (size_t)(b * 196) * sv + h * 64;
    for (int e = t; e < 196 * 8; e += 256) {
        const int kk = e >> 3, ch = e & 7;
        uint4 v = *(const uint4*)(vrsrc + (size_t)kk * sv + ch * 8);
        unsigned short vs[8]; *(uint4*)vs = v;
#pragma unroll
        for (int j = 0; j < 8; j++) sVT[(ch * 8 + j) * 232 + kk] = vs[j];
    }
    for (int e = t; e < 64 * 36; e += 256) sVT[(e / 36) * 232 + 196 + (e % 36)] = 0;
    // zero own-wave sR pad cols 208..231 (cols 196..207 = relu(0) from kt=12)
    for (int e = l; e < 16 * 24; e += 64) sRw[(e / 24) * 232 + 208 + (e % 24)] = 0;

    // q2 fragments in registers: lane (lr,lk) holds q2[kt*16+lr][ck*32 + lk*8]
    bf16x8 qf0[13], qf1[13];
    const unsigned short* q2src = Q2b + (size_t)(b * 196) * sq + h * 64;
#pragma unroll
    for (int kt = 0; kt < 13; kt++) {
        const int r = kt * 16 + lr;
        if (r < 196) {
            const unsigned short* p = q2src + (size_t)r * sq;
            qf0[kt] = *(const bf16x8*)(p + lk * 8);
            qf1[kt] = *(const bf16x8*)(p + 32 + lk * 8);
        } else {
            qf0[kt] = (bf16x8){0, 0, 0, 0, 0, 0, 0, 0};
            qf1[kt] = (bf16x8){0, 0, 0, 0, 0, 0, 0, 0};
        }
    }
    __syncthreads();   // sVT visible to all waves (only barrier in kernel)

    const unsigned short* k2src = K2b + (size_t)(c * 196) * sk + h * 64;
    unsigned short* zdst = Zt + ((((size_t)(b * 6 + h)) * 10 + c) * 64) * 208;

    for (int mt = w; mt < 13; mt += 4) {
        // k2 a-fragments for this m-tile (rows >=196 zeroed)
        bf16x8 a0, a1;
        const int ar = mt * 16 + lr;
        if (ar < 196) {
            const unsigned short* p = k2src + (size_t)ar * sk;
            a0 = *(const bf16x8*)(p + lk * 8);
            a1 = *(const bf16x8*)(p + 32 + lk * 8);
        } else {
            a0 = (bf16x8){0, 0, 0, 0, 0, 0, 0, 0};
            a1 = (bf16x8){0, 0, 0, 0, 0, 0, 0, 0};
        }
        // S strip: 13 x (16x16) -> relu -> wave-private sR tile
#pragma unroll
        for (int kt = 0; kt < 13; kt++) {
            f32x4 acc = {0.f, 0.f, 0.f, 0.f};
            acc = MFMA16(a0, qf0[kt], acc);
            acc = MFMA16(a1, qf1[kt], acc);
#pragma unroll
            for (int i = 0; i < 4; i++)
                sRw[(lk * 4 + i) * 232 + kt * 16 + lr] = f2bf(fmaxf(0.f, SCL * acc[i]));
        }
        // Z tile: [16][64] = R_tile @ vr  (K = 224 = 7 chunks); store Zt[d][m]
#pragma unroll
        for (int dt = 0; dt < 4; dt++) {
            f32x4 acc = {0.f, 0.f, 0.f, 0.f};
#pragma unroll
            for (int kc = 0; kc < 7; kc++) {
                bf16x8 a  = *(const bf16x8*)&sRw[lr * 232 + kc * 32 + lk * 8];
                bf16x8 bb = *(const bf16x8*)&sVT[(dt * 16 + lr) * 232 + kc * 32 + lk * 8];
                acc = MFMA16(a, bb, acc);
            }
            unsigned short p[4];
#pragma unroll
            for (int i = 0; i < 4; i++) p[i] = f2bf(acc[i]);
            *(uint2*)&zdst[(size_t)(dt * 16 + lr) * 208 + mt * 16 + lk * 4] = *(uint2*)p;
        }
    }
}

// ===========================================================================
// MFMA chain, stage B (round 8 verified: 2 blocks/CU, Q in registers).
// ===========================================================================
__global__ __launch_bounds__(256)
void yz_kernel(const unsigned short* __restrict__ QHb, const unsigned short* __restrict__ KHb,
               const unsigned short* __restrict__ Zt, const float* __restrict__ aflat,
               unsigned short* __restrict__ rect) {
    const int ns = blockIdx.x, h = blockIdx.y, b = blockIdx.z;
    const int n0 = ns * 49;
    const int t = threadIdx.x;
    const int w = t >> 6, l = t & 63;
    const int lr = l & 15, lk = l >> 4;

    __shared__ unsigned short sKH[112 * 72];   // 16,128 B (KH m-half)
    __shared__ unsigned short sZT[64 * 232];   // 29,696 B
    __shared__ unsigned short sL[64 * 232];    // 29,696 B -> total 75,520 B

    for (int e = t; e < 64 * 24; e += 256) {
        sZT[(e / 24) * 232 + 208 + (e % 24)] = 0;
        sL [(e / 24) * 232 + 208 + (e % 24)] = 0;
    }

    bf16x8 qf[2];
    {
        const int rel = w * 16 + lr;
        if (rel < 49) {
            const unsigned short* qsrc = QHb + (size_t)(b * 196 + n0 + rel) * 1152 + h * 64;
            qf[0] = *(const bf16x8*)(qsrc + lk * 8);
            qf[1] = *(const bf16x8*)(qsrc + 32 + lk * 8);
        } else {
            qf[0] = (bf16x8){0, 0, 0, 0, 0, 0, 0, 0};
            qf[1] = (bf16x8){0, 0, 0, 0, 0, 0, 0, 0};
        }
    }

    f32x4 y[4];
#pragma unroll
    for (int i = 0; i < 4; i++) y[i] = (f32x4){0.f, 0.f, 0.f, 0.f};
    __syncthreads();

    for (int c = 0; c < 10; c++) {
        const unsigned short* zsrc = Zt + ((((size_t)(b * 6 + h)) * 10 + c) * 64) * 208;
        for (int e = t; e < 64 * 26; e += 256) {
            const int d = e / 26, mc = e % 26;
            *(uint4*)&sZT[d * 232 + mc * 8] = *(const uint4*)(zsrc + (size_t)d * 208 + mc * 8);
        }
        for (int e = t; e < 112 * 8; e += 256) {
            const int r = e >> 3, ch = e & 7;
            *(uint4*)&sKH[r * 72 + ch * 8] =
                *(const uint4*)(KHb + (size_t)(c * 196 + r) * 768 + h * 64 + ch * 8);
        }
        const float wc = aflat[b * 60 + h * 10 + c];
        __syncthreads();
#pragma unroll
        for (int mt = 0; mt < 7; mt++) {
            f32x4 acc = {0.f, 0.f, 0.f, 0.f};
            bf16x8 b0 = *(const bf16x8*)&sKH[(mt * 16 + lr) * 72 + lk * 8];
            acc = MFMA16(qf[0], b0, acc);
            bf16x8 b1 = *(const bf16x8*)&sKH[(mt * 16 + lr) * 72 + 32 + lk * 8];
            acc = MFMA16(qf[1], b1, acc);
            const int lrow = w * 16 + lk * 4, lcol = mt * 16 + lr;
#pragma unroll
            for (int i = 0; i < 4; i++)
                sL[(lrow + i) * 232 + lcol] = f2bf(wc * fmaxf(0.f, -SCL * acc[i]));
        }
        __syncthreads();
        for (int e = t; e < 96 * 8; e += 256) {
            const int r = e >> 3, ch = e & 7;
            uint4 v = make_uint4(0, 0, 0, 0);
            if (112 + r < 196)
                v = *(const uint4*)(KHb + (size_t)(c * 196 + 112 + r) * 768 + h * 64 + ch * 8);
            *(uint4*)&sKH[r * 72 + ch * 8] = v;
        }
        __syncthreads();
#pragma unroll
        for (int mt = 7; mt < 13; mt++) {
            f32x4 acc = {0.f, 0.f, 0.f, 0.f};
            bf16x8 b0 = *(const bf16x8*)&sKH[((mt - 7) * 16 + lr) * 72 + lk * 8];
            acc = MFMA16(qf[0], b0, acc);
            bf16x8 b1 = *(const bf16x8*)&sKH[((mt - 7) * 16 + lr) * 72 + 32 + lk * 8];
            acc = MFMA16(qf[1], b1, acc);
            const int lrow = w * 16 + lk * 4, lcol = mt * 16 + lr;
#pragma unroll
            for (int i = 0; i < 4; i++)
                sL[(lrow + i) * 232 + lcol] = f2bf(wc * fmaxf(0.f, -SCL * acc[i]));
        }
#pragma unroll
        for (int dt = 0; dt < 4; dt++) {
            f32x4 acc = y[dt];
#pragma unroll
            for (int mc = 0; mc < 7; mc++) {
                bf16x8 a  = *(const bf16x8*)&sL[(w * 16 + lr) * 232 + mc * 32 + lk * 8];
                bf16x8 bb = *(const bf16x8*)&sZT[(dt * 16 + lr) * 232 + mc * 32 + lk * 8];
                acc = MFMA16(a, bb, acc);
            }
            y[dt] = acc;
        }
        __syncthreads();
    }

#pragma unroll
    for (int dt = 0; dt < 4; dt++)
#pragma unroll
        for (int i = 0; i < 4; i++) {
            const int rel = w * 16 + lk * 4 + i;
            if (rel < 49)
                rect[(((size_t)(b * 6 + h)) * 196 + n0 + rel) * 64 + dt * 16 + lr] = f2bf(y[dt][i]);
        }
}

// ---------------------------------------------------------------------------
// Copy anchors verbatim.
// ---------------------------------------------------------------------------
__global__ void copy_anchors(const float* __restrict__ x, float* __restrict__ out) {
    const int e = blockIdx.x * 256 + threadIdx.x;
    if (e < 189120) {
        const int base = 16 * 197 * 384 / 4;
        ((float4*)out)[base + e] = ((const float4*)x)[base + e];
    }
}

// ---------------------------------------------------------------------------
// kernel_launch. Workspace in f32 units, total 12,655,296 f = 50.6 MB.
// Layout: Px | Pa | rect | xx | Wx_t | Wr_t | W1_t | W2_t | Zt (hdn/G alias
// Zt, dead after yz). No overlaps among live ranges (round-7 bug fixed).
// ---------------------------------------------------------------------------
extern "C" void kernel_launch(void* const* d_in, const int* in_sizes, int n_in,
                              void* d_out, int out_size, void* d_ws, size_t ws_size,
                              hipStream_t stream) {
    (void)in_sizes; (void)n_in; (void)out_size; (void)ws_size;
    const float* x       = (const float*)d_in[0];
    const float* Wqv     = (const float*)d_in[1];
    const float* Wk      = (const float*)d_in[2];
    const float* Wq_proj = (const float*)d_in[3];
    const float* bq_proj = (const float*)d_in[4];
    const float* Wqk     = (const float*)d_in[5];
    const float* Wqk2    = (const float*)d_in[6];
    const float* Wv      = (const float*)d_in[7];
    const float* Wr_proj = (const float*)d_in[8];
    const float* br_proj = (const float*)d_in[9];
    const float* g1      = (const float*)d_in[10];
    const float* b1      = (const float*)d_in[11];
    const float* g2      = (const float*)d_in[12];
    const float* b2      = (const float*)d_in[13];
    const float* g3      = (const float*)d_in[14];
    const float* b3      = (const float*)d_in[15];
    const float* W1      = (const float*)d_in[16];
    const float* bm1     = (const float*)d_in[17];
    const float* W2      = (const float*)d_in[18];
    const float* bm2     = (const float*)d_in[19];

    float* ws = (float*)d_ws;
    float* n1      = ws;                                       //      9,984
    float* qv      = ws + 9984;                                //      7,680
    float* kcls    = ws + 17664;                               //      6,144
    float* aflat   = ws + 23808;                               //        960
    float* cls_pre = ws + 24768;                               //      6,144
    unsigned short* n2x_bf  = (unsigned short*)(ws + 30912);   // 3136x384 bf16  [ends   633,024]
    unsigned short* n2a_bf  = (unsigned short*)(ws + 633024);  // 1960x384 bf16  [ends 1,009,344]
    unsigned short* Px      = (unsigned short*)(ws + 1009344); // 3136x1152 bf16 [ends 2,815,680]
    unsigned short* Pa      = (unsigned short*)(ws + 2815680); // 1960x768 bf16  [ends 3,568,320]
    unsigned short* rect_bf = (unsigned short*)(ws + 3568320); // 3136x384 bf16  [ends 4,170,432]
    float* xx               = ws + 4170432;                    // 16x197x384 f32 [ends 5,380,800]
    unsigned short* Wx_t    = (unsigned short*)(ws + 5380800); // 1152x384 bf16  [ends 5,601,984]
    unsigned short* Wr_t    = (unsigned short*)(ws + 5601984); // 384x384 bf16   [ends 5,675,712]
    unsigned short* W1_t    = (unsigned short*)(ws + 5675712); // 1536x384 bf16  [ends 5,970,624]
    unsigned short* W2_t    = (unsigned short*)(ws + 5970624); // 384x1536 bf16  [ends 6,265,536]
    unsigned short* Zt      = (unsigned short*)(ws + 6265536); // 96*10*64*208   [ends 12,655,296]
    unsigned short* hdn_bf  = (unsigned short*)(ws + 6265536); // alias Zt (dead after yz)
    unsigned short* G_bf    = (unsigned short*)(ws + 6870720); // alias Zt region
    float* outf = (float*)d_out;

    // column-slice views of the fused projection buffers
    unsigned short* QHb = Px;           // stride 1152
    unsigned short* Q2b = Px + 384;
    unsigned short* VRb = Px + 768;
    unsigned short* KHb = Pa;           // stride 768
    unsigned short* K2b = Pa + 384;

    // 0. weight transpose-casts
    wcast3<<<dim3(6, 6, 3), 256, 0, stream>>>(Wqk, Wqk2, Wv, Wx_t);
    wcast_t<<<dim3(6, 6),  256, 0, stream>>>(Wr_proj, Wr_t, 384, 384);
    wcast_t<<<dim3(24, 6), 256, 0, stream>>>(W1, W1_t, 384, 1536);
    wcast_t<<<dim3(6, 24), 256, 0, stream>>>(W2, W2_t, 1536, 384);
    // 1. LN cls tokens (fp32 out)
    ln_kernel<0><<<26, 64, 0, stream>>>(x, n1, g1, b1, 0);
    // 2. qv / kcls (latency-optimized cls GEMMs)
    gemm_cls<10><<<12, 256, 0, stream>>>(n1 + 16 * 384, Wqv, nullptr, qv, 768, 768);
    gemm_cls<16><<<6, 256, 0, stream>>>(n1, Wk, nullptr, kcls, 384, 384);
    // 3. cls attention
    attn_cls_kernel<<<16, 64, 0, stream>>>(qv, kcls, aflat, cls_pre);
    // 4. LN image tokens, xs + anchors fused in ONE launch (contiguous dst)
    ln_kernel<1><<<5096, 64, 0, stream>>>(x, n2x_bf, g2, b2, 4);
    // 5. fused head projections: Px = n2x @ [Wqk|Wqk2|Wv]; Pa = n2a @ [Wqk|Wqk2]
    gemm_mfma<0><<<dim3(9, 49), 256, 0, stream>>>(n2x_bf, Wx_t, nullptr, nullptr, Px, 3136, 1152, 384);
    gemm_mfma<0><<<dim3(6, 31), 256, 0, stream>>>(n2a_bf, Wx_t, nullptr, nullptr, Pa, 1960, 768, 384);
    // 6. chain stage A (v2, fused per-wave S->R->Z)
    rz_kernel<<<dim3(10, 6, 16), 256, 0, stream>>>(Q2b, K2b, VRb, Zt, 1152, 768, 1152);
    // 7. chain stage B -> rect bf16 (reshape layout)
    yz_kernel<<<dim3(4, 6, 16), 256, 0, stream>>>(QHb, KHb, Zt, aflat, rect_bf);
    // 8. cls_out -> xx token 0
    gemm_cls<16><<<6, 256, 0, stream>>>(cls_pre, Wq_proj, bq_proj, xx, 384, 197 * 384);
    // 9. xx[:,1:] = rect @ Wr_proj + br + x_im  (remapped rows)
    gemm_mfma<1><<<dim3(3, 49), 256, 0, stream>>>(rect_bf, Wr_t, br_proj, x, xx, 3136, 384, 384);
    // 10. LN3 (bf16 out into hdn)
    ln_kernel<1><<<3152, 64, 0, stream>>>(xx, hdn_bf, g3, b3, 3);
    // 11. MLP up + GELU -> bf16 G
    gemm_mfma<2><<<dim3(12, 50), 256, 0, stream>>>(hdn_bf, W1_t, bm1, nullptr, G_bf, 3152, 1536, 384);
    // 12. MLP down + bias + residual -> out rows 0..3151
    gemm_mfma<3><<<dim3(3, 50), 256, 0, stream>>>(G_bf, W2_t, bm2, xx, outf, 3152, 384, 1536);
    // 13. anchors pass-through
    copy_anchors<<<739, 256, 0, stream>>>(x, outf);
}